// Round 2
// baseline (4666.095 us; speedup 1.0000x reference)
//
#include <hip/hip_runtime.h>
#include <math.h>

#define N_NODES 50000
#define N_EDGESX 800000
#define E_TOT   (N_EDGESX + N_NODES)
#define HEADS 8
#define HID 64
#define HH512 (HID*HEADS)     // 512
#define OUTC 47
#define NEG_SLOPE 0.2f

__device__ __forceinline__ float lrelu(float x) { return x > 0.f ? x : NEG_SLOPE * x; }

// float atomic max via monotone int mapping (values are finite; init is -inf)
__device__ __forceinline__ void atomicMaxF(float* addr, float val) {
    if (val >= 0.f) atomicMax((int*)addr, __float_as_int(val));
    else            atomicMin((unsigned int*)addr, __float_as_uint(val));
}

__device__ __forceinline__ void edge_sd(const int* __restrict__ ei, int e, int& s, int& d) {
    if (e < N_EDGESX) { s = ei[e]; d = ei[N_EDGESX + e]; }
    else              { s = e - N_EDGESX; d = e - N_EDGESX; }
}

// ---------------- GEMM: C[M,N] = A[M,K] * B[K,N], f32, 64x64 tile ----------------
#define TS 64
#define BK 16
__global__ __launch_bounds__(256) void gemm_f32(const float* __restrict__ A,
                                                const float* __restrict__ B,
                                                float* __restrict__ C,
                                                int M, int N, int K) {
    __shared__ float As[BK][TS + 1];
    __shared__ float Bs[BK][TS + 1];
    int tidx = threadIdx.x;
    int brow = blockIdx.x * TS;
    int bcol = blockIdx.y * TS;
    int tc = tidx & 15, tr = tidx >> 4;
    float acc[4][4] = {};
    for (int k0 = 0; k0 < K; k0 += BK) {
        #pragma unroll
        for (int i = tidx; i < TS * BK; i += 256) {
            int m = i >> 4, k = i & 15;       // k fastest -> coalesced-ish A row chunks
            int row = brow + m;
            As[k][m] = (row < M) ? A[(size_t)row * K + k0 + k] : 0.f;
        }
        #pragma unroll
        for (int i = tidx; i < TS * BK; i += 256) {
            int n = i & 63, k = i >> 6;       // n fastest -> coalesced B rows
            int col = bcol + n;
            Bs[k][n] = (col < N) ? B[(size_t)(k0 + k) * N + col] : 0.f;
        }
        __syncthreads();
        #pragma unroll
        for (int k = 0; k < BK; ++k) {
            float a[4], b[4];
            #pragma unroll
            for (int i = 0; i < 4; ++i) a[i] = As[k][tr * 4 + i];
            #pragma unroll
            for (int j = 0; j < 4; ++j) b[j] = Bs[k][tc * 4 + j];
            #pragma unroll
            for (int i = 0; i < 4; ++i)
                #pragma unroll
                for (int j = 0; j < 4; ++j) acc[i][j] += a[i] * b[j];
        }
        __syncthreads();
    }
    #pragma unroll
    for (int i = 0; i < 4; ++i) {
        int row = brow + tr * 4 + i;
        if (row >= M) continue;
        #pragma unroll
        for (int j = 0; j < 4; ++j) {
            int col = bcol + tc * 4 + j;
            if (col < N) C[(size_t)row * N + col] = acc[i][j];
        }
    }
}

// ---------------- attention logits: als/ald[n,h] = sum_c h[n,h,c]*a[h,c] ----------------
__global__ void attn_logits_k(const float* __restrict__ h, const float* __restrict__ a_s,
                              const float* __restrict__ a_d, float* __restrict__ als,
                              float* __restrict__ ald, int HH, int C) {
    int t = blockIdx.x * blockDim.x + threadIdx.x;
    int wid = t >> 6, lane = threadIdx.x & 63;
    if (wid >= N_NODES * HH) return;
    int n = wid / HH, hh = wid % HH;
    float hv = (lane < C) ? h[(size_t)n * HH * C + hh * C + lane] : 0.f;
    float vs = (lane < C) ? hv * a_s[hh * C + lane] : 0.f;
    float vd = (lane < C) ? hv * a_d[hh * C + lane] : 0.f;
    #pragma unroll
    for (int off = 32; off; off >>= 1) {
        vs += __shfl_down(vs, off);
        vd += __shfl_down(vd, off);
    }
    if (lane == 0) { als[wid] = vs; ald[wid] = vd; }
}

__global__ void fill_k(float* __restrict__ p, int n, float v) {
    int i = blockIdx.x * blockDim.x + threadIdx.x;
    if (i < n) p[i] = v;
}

// ---------------- edge pass A: segment max ----------------
template <int HH>
__global__ void edge_max_k(const int* __restrict__ ei, const float* __restrict__ als,
                           const float* __restrict__ ald, float* __restrict__ m) {
    long long t = (long long)blockIdx.x * blockDim.x + threadIdx.x;
    if (t >= (long long)E_TOT * HH) return;
    int e = (int)(t / HH), hh = (int)(t % HH);
    int s, d; edge_sd(ei, e, s, d);
    float v = lrelu(als[s * HH + hh] + ald[d * HH + hh]);
    atomicMaxF(&m[d * HH + hh], v);
}

// ---------------- edge pass B: segment sum of exp ----------------
template <int HH>
__global__ void edge_sum_k(const int* __restrict__ ei, const float* __restrict__ als,
                           const float* __restrict__ ald, const float* __restrict__ m,
                           float* __restrict__ den) {
    long long t = (long long)blockIdx.x * blockDim.x + threadIdx.x;
    if (t >= (long long)E_TOT * HH) return;
    int e = (int)(t / HH), hh = (int)(t % HH);
    int s, d; edge_sd(ei, e, s, d);
    float mv = m[d * HH + hh];
    if (mv == -INFINITY) mv = 0.f;
    float v = lrelu(als[s * HH + hh] + ald[d * HH + hh]);
    atomicAdd(&den[d * HH + hh], expf(v - mv));
}

// ---------------- edge pass C: weighted scatter-aggregate ----------------
template <int HH, int C>
__global__ void edge_agg_k(const int* __restrict__ ei, const float* __restrict__ als,
                           const float* __restrict__ ald, const float* __restrict__ m,
                           const float* __restrict__ den, const float* __restrict__ hf,
                           float* __restrict__ out) {
    long long t = (long long)blockIdx.x * blockDim.x + threadIdx.x;
    long long wid = t >> 6;
    int lane = threadIdx.x & 63;
    if (wid >= (long long)E_TOT * HH) return;
    int e = (int)(wid / HH), hh = (int)(wid % HH);
    int s, d; edge_sd(ei, e, s, d);
    float mv = m[d * HH + hh];
    if (mv == -INFINITY) mv = 0.f;
    float v = lrelu(als[s * HH + hh] + ald[d * HH + hh]);
    float alpha = expf(v - mv) / (den[d * HH + hh] + 1e-16f);
    if (lane < C) {
        float msg = hf[(size_t)s * (HH * C) + hh * C + lane] * alpha;
        atomicAdd(&out[(size_t)d * (HH * C) + hh * C + lane], msg);
    }
}

__global__ void bias_relu_k(float* __restrict__ y, const float* __restrict__ b,
                            long long n, int C /* pow2 */) {
    long long i = (long long)blockIdx.x * blockDim.x + threadIdx.x;
    if (i < n) {
        float v = y[i] + b[(int)(i & (C - 1))];
        y[i] = v > 0.f ? v : 0.f;
    }
}

// ---------------- final: out = log_softmax(agg + bias) per row of 47 ----------------
__global__ void log_softmax_k(float* __restrict__ out, const float* __restrict__ b, int C) {
    int t = blockIdx.x * blockDim.x + threadIdx.x;
    int wid = t >> 6, lane = threadIdx.x & 63;
    if (wid >= N_NODES) return;
    float v = (lane < C) ? out[(size_t)wid * C + lane] + b[lane] : -INFINITY;
    float mx = v;
    #pragma unroll
    for (int off = 32; off; off >>= 1) mx = fmaxf(mx, __shfl_xor(mx, off));
    float ex = (lane < C) ? expf(v - mx) : 0.f;
    float sum = ex;
    #pragma unroll
    for (int off = 32; off; off >>= 1) sum += __shfl_xor(sum, off);
    if (lane < C) out[(size_t)wid * C + lane] = v - mx - logf(sum);
}

static inline int cdiv(long long a, long long b) { return (int)((a + b - 1) / b); }

extern "C" void kernel_launch(void* const* d_in, const int* in_sizes, int n_in,
                              void* d_out, int out_size, void* d_ws, size_t ws_size,
                              hipStream_t stream) {
    const float* x   = (const float*)d_in[0];
    const int*   ei  = (const int*)d_in[1];
    const float* W1  = (const float*)d_in[2];
    const float* as1 = (const float*)d_in[3];
    const float* ad1 = (const float*)d_in[4];
    const float* b1  = (const float*)d_in[5];
    const float* W2  = (const float*)d_in[6];
    const float* as2 = (const float*)d_in[7];
    const float* ad2 = (const float*)d_in[8];
    const float* b2  = (const float*)d_in[9];
    const float* W3  = (const float*)d_in[10];
    const float* as3 = (const float*)d_in[11];
    const float* ad3 = (const float*)d_in[12];
    const float* b3  = (const float*)d_in[13];
    float* out = (float*)d_out;

    float* Hb  = (float*)d_ws;                       // [N,512]
    float* Xb  = Hb + (size_t)N_NODES * HH512;       // [N,512]
    float* als = Xb + (size_t)N_NODES * HH512;       // [N,8]
    float* ald = als + (size_t)N_NODES * HEADS;
    float* mb  = ald + (size_t)N_NODES * HEADS;
    float* db  = mb  + (size_t)N_NODES * HEADS;

    dim3 blk(256);

    // ================= Layer 1 : x[N,256] -> Xb[N,512] =================
    gemm_f32<<<dim3(cdiv(N_NODES, 64), 8), blk, 0, stream>>>(x, W1, Hb, N_NODES, HH512, 256);
    attn_logits_k<<<cdiv((long long)N_NODES * HEADS * 64, 256), blk, 0, stream>>>(Hb, as1, ad1, als, ald, HEADS, 64);
    fill_k<<<cdiv(N_NODES * HEADS, 256), blk, 0, stream>>>(mb, N_NODES * HEADS, -INFINITY);
    hipMemsetAsync(db, 0, (size_t)N_NODES * HEADS * 4, stream);
    hipMemsetAsync(Xb, 0, (size_t)N_NODES * HH512 * 4, stream);
    edge_max_k<HEADS><<<cdiv((long long)E_TOT * HEADS, 256), blk, 0, stream>>>(ei, als, ald, mb);
    edge_sum_k<HEADS><<<cdiv((long long)E_TOT * HEADS, 256), blk, 0, stream>>>(ei, als, ald, mb, db);
    edge_agg_k<HEADS, 64><<<cdiv((long long)E_TOT * HEADS * 64, 256), blk, 0, stream>>>(ei, als, ald, mb, db, Hb, Xb);
    bias_relu_k<<<cdiv((long long)N_NODES * HH512, 256), blk, 0, stream>>>(Xb, b1, (long long)N_NODES * HH512, 512);

    // ================= Layer 2 : Xb[N,512] -> Xb[N,512] =================
    gemm_f32<<<dim3(cdiv(N_NODES, 64), 8), blk, 0, stream>>>(Xb, W2, Hb, N_NODES, HH512, HH512);
    attn_logits_k<<<cdiv((long long)N_NODES * HEADS * 64, 256), blk, 0, stream>>>(Hb, as2, ad2, als, ald, HEADS, 64);
    fill_k<<<cdiv(N_NODES * HEADS, 256), blk, 0, stream>>>(mb, N_NODES * HEADS, -INFINITY);
    hipMemsetAsync(db, 0, (size_t)N_NODES * HEADS * 4, stream);
    hipMemsetAsync(Xb, 0, (size_t)N_NODES * HH512 * 4, stream);  // Xb consumed by gemm above
    edge_max_k<HEADS><<<cdiv((long long)E_TOT * HEADS, 256), blk, 0, stream>>>(ei, als, ald, mb);
    edge_sum_k<HEADS><<<cdiv((long long)E_TOT * HEADS, 256), blk, 0, stream>>>(ei, als, ald, mb, db);
    edge_agg_k<HEADS, 64><<<cdiv((long long)E_TOT * HEADS * 64, 256), blk, 0, stream>>>(ei, als, ald, mb, db, Hb, Xb);
    bias_relu_k<<<cdiv((long long)N_NODES * HH512, 256), blk, 0, stream>>>(Xb, b2, (long long)N_NODES * HH512, 512);

    // ================= Layer 3 : Xb[N,512] -> out[N,47] =================
    gemm_f32<<<dim3(cdiv(N_NODES, 64), 1), blk, 0, stream>>>(Xb, W3, Hb, N_NODES, OUTC, HH512);
    attn_logits_k<<<cdiv((long long)N_NODES * 64, 256), blk, 0, stream>>>(Hb, as3, ad3, als, ald, 1, OUTC);
    fill_k<<<cdiv(N_NODES, 256), blk, 0, stream>>>(mb, N_NODES, -INFINITY);
    hipMemsetAsync(db, 0, (size_t)N_NODES * 4, stream);
    hipMemsetAsync(out, 0, (size_t)N_NODES * OUTC * 4, stream);
    edge_max_k<1><<<cdiv((long long)E_TOT, 256), blk, 0, stream>>>(ei, als, ald, mb);
    edge_sum_k<1><<<cdiv((long long)E_TOT, 256), blk, 0, stream>>>(ei, als, ald, mb, db);
    edge_agg_k<1, OUTC><<<cdiv((long long)E_TOT * 64, 256), blk, 0, stream>>>(ei, als, ald, mb, db, Hb, out);
    log_softmax_k<<<cdiv((long long)N_NODES * 64, 256), blk, 0, stream>>>(out, b3, OUTC);
}

// Round 7
// 2353.638 us; speedup vs baseline: 1.9825x; 1.9825x over previous
//
#include <hip/hip_runtime.h>
#include <math.h>

#define N_NODES 50000
#define N_EDGESX 800000
#define E_TOT   (N_EDGESX + N_NODES)
#define HEADS 8
#define HID 64
#define HH512 (HID*HEADS)     // 512
#define OUTC 47
#define NEG_SLOPE 0.2f

__device__ __forceinline__ float lrelu(float x) { return x > 0.f ? x : NEG_SLOPE * x; }

// ---------------- GEMM: C[M,N] = A[M,K] * B[K,N], f32, 64x64 tile ----------------
#define TS 64
#define BK 16
__global__ __launch_bounds__(256) void gemm_f32(const float* __restrict__ A,
                                                const float* __restrict__ B,
                                                float* __restrict__ C,
                                                int M, int N, int K) {
    __shared__ float As[BK][TS + 1];
    __shared__ float Bs[BK][TS + 1];
    int tidx = threadIdx.x;
    int brow = blockIdx.x * TS;
    int bcol = blockIdx.y * TS;
    int tc = tidx & 15, tr = tidx >> 4;
    float acc[4][4] = {};
    for (int k0 = 0; k0 < K; k0 += BK) {
        #pragma unroll
        for (int i = tidx; i < TS * BK; i += 256) {
            int m = i >> 4, k = i & 15;
            int row = brow + m;
            As[k][m] = (row < M) ? A[(size_t)row * K + k0 + k] : 0.f;
        }
        #pragma unroll
        for (int i = tidx; i < TS * BK; i += 256) {
            int n = i & 63, k = i >> 6;
            int col = bcol + n;
            Bs[k][n] = (col < N) ? B[(size_t)(k0 + k) * N + col] : 0.f;
        }
        __syncthreads();
        #pragma unroll
        for (int k = 0; k < BK; ++k) {
            float a[4], b[4];
            #pragma unroll
            for (int i = 0; i < 4; ++i) a[i] = As[k][tr * 4 + i];
            #pragma unroll
            for (int j = 0; j < 4; ++j) b[j] = Bs[k][tc * 4 + j];
            #pragma unroll
            for (int i = 0; i < 4; ++i)
                #pragma unroll
                for (int j = 0; j < 4; ++j) acc[i][j] += a[i] * b[j];
        }
        __syncthreads();
    }
    #pragma unroll
    for (int i = 0; i < 4; ++i) {
        int row = brow + tr * 4 + i;
        if (row >= M) continue;
        #pragma unroll
        for (int j = 0; j < 4; ++j) {
            int col = bcol + tc * 4 + j;
            if (col < N) C[(size_t)row * N + col] = acc[i][j];
        }
    }
}

// ---------------- attention logits: als/ald[n,h] = sum_c h[n,h,c]*a[h,c] ----------------
__global__ void attn_logits_k(const float* __restrict__ h, const float* __restrict__ a_s,
                              const float* __restrict__ a_d, float* __restrict__ als,
                              float* __restrict__ ald, int HH, int C) {
    int t = blockIdx.x * blockDim.x + threadIdx.x;
    int wid = t >> 6, lane = threadIdx.x & 63;
    if (wid >= N_NODES * HH) return;
    int n = wid / HH, hh = wid % HH;
    float hv = (lane < C) ? h[(size_t)n * HH * C + hh * C + lane] : 0.f;
    float vs = (lane < C) ? hv * a_s[hh * C + lane] : 0.f;
    float vd = (lane < C) ? hv * a_d[hh * C + lane] : 0.f;
    #pragma unroll
    for (int off = 32; off; off >>= 1) {
        vs += __shfl_down(vs, off);
        vd += __shfl_down(vd, off);
    }
    if (lane == 0) { als[wid] = vs; ald[wid] = vd; }
}

// ---------------- CSR build ----------------
__global__ void deg_count_k(const int* __restrict__ ei, int* __restrict__ deg) {
    int e = blockIdx.x * blockDim.x + threadIdx.x;
    if (e >= E_TOT) return;
    int d = (e < N_EDGESX) ? ei[N_EDGESX + e] : e - N_EDGESX;
    atomicAdd(&deg[d], 1);
}

// single-block exclusive scan: pos holds degrees on entry, exclusive prefix on exit
__global__ __launch_bounds__(1024) void scan_k(int* __restrict__ pos, int* __restrict__ rowptr) {
    __shared__ int buf[1024];
    __shared__ int carry;
    if (threadIdx.x == 0) carry = 0;
    __syncthreads();
    for (int base = 0; base < N_NODES; base += 1024) {
        int i = base + threadIdx.x;
        int v = (i < N_NODES) ? pos[i] : 0;
        buf[threadIdx.x] = v;
        __syncthreads();
        for (int off = 1; off < 1024; off <<= 1) {
            int t = (threadIdx.x >= off) ? buf[threadIdx.x - off] : 0;
            __syncthreads();
            buf[threadIdx.x] += t;
            __syncthreads();
        }
        int excl = buf[threadIdx.x] - v + carry;
        if (i < N_NODES) { rowptr[i] = excl; pos[i] = excl; }
        __syncthreads();
        if (threadIdx.x == 1023) carry += buf[1023];
        __syncthreads();
    }
    if (threadIdx.x == 0) rowptr[N_NODES] = carry;
}

__global__ void scatter_k(const int* __restrict__ ei, int* __restrict__ pos,
                          int* __restrict__ csr_src) {
    int e = blockIdx.x * blockDim.x + threadIdx.x;
    if (e >= E_TOT) return;
    int s, d;
    if (e < N_EDGESX) { s = ei[e]; d = ei[N_EDGESX + e]; }
    else              { s = e - N_EDGESX; d = s; }
    int idx = atomicAdd(&pos[d], 1);
    csr_src[idx] = s;
}

// ---------------- fused per-node softmax + aggregate, H=8, C=64 (+bias+ReLU) ----------------
__global__ __launch_bounds__(256) void node_agg8_k(
    const int* __restrict__ rowptr, const int* __restrict__ csr_src,
    const float* __restrict__ als, const float* __restrict__ ald,
    const float* __restrict__ hf, const float* __restrict__ bias,
    float* __restrict__ out) {
    int node = (blockIdx.x << 2) + (threadIdx.x >> 6);
    int lane = threadIdx.x & 63;
    if (node >= N_NODES) return;
    int beg = rowptr[node], end = rowptr[node + 1];
    float4 d0 = *(const float4*)(ald + (size_t)node * 8);
    float4 d1 = *(const float4*)(ald + (size_t)node * 8 + 4);
    float adv[8] = {d0.x, d0.y, d0.z, d0.w, d1.x, d1.y, d1.z, d1.w};
    float m[8];
    #pragma unroll
    for (int j = 0; j < 8; ++j) m[j] = -INFINITY;
    for (int i = beg; i < end; ++i) {
        int s = csr_src[i];
        float4 s0 = *(const float4*)(als + (size_t)s * 8);
        float4 s1 = *(const float4*)(als + (size_t)s * 8 + 4);
        float sv[8] = {s0.x, s0.y, s0.z, s0.w, s1.x, s1.y, s1.z, s1.w};
        #pragma unroll
        for (int j = 0; j < 8; ++j) m[j] = fmaxf(m[j], lrelu(sv[j] + adv[j]));
    }
    float den[8] = {}, acc[8] = {};
    for (int i = beg; i < end; ++i) {
        int s = csr_src[i];
        float4 s0 = *(const float4*)(als + (size_t)s * 8);
        float4 s1 = *(const float4*)(als + (size_t)s * 8 + 4);
        float sv[8] = {s0.x, s0.y, s0.z, s0.w, s1.x, s1.y, s1.z, s1.w};
        const float* hrow = hf + (size_t)s * HH512;
        #pragma unroll
        for (int j = 0; j < 8; ++j) {
            float p = expf(lrelu(sv[j] + adv[j]) - m[j]);
            den[j] += p;
            acc[j] += p * hrow[j * 64 + lane];
        }
    }
    size_t ob = (size_t)node * HH512;
    #pragma unroll
    for (int j = 0; j < 8; ++j) {
        float r = acc[j] / (den[j] + 1e-16f) + bias[j * 64 + lane];
        out[ob + j * 64 + lane] = fmaxf(r, 0.f);
    }
}

// ---------------- final layer: H=1, C=47, fused bias + log_softmax ----------------
__global__ __launch_bounds__(256) void node_agg_final_k(
    const int* __restrict__ rowptr, const int* __restrict__ csr_src,
    const float* __restrict__ als, const float* __restrict__ ald,
    const float* __restrict__ hf, const float* __restrict__ b3,
    float* __restrict__ out) {
    int node = (blockIdx.x << 2) + (threadIdx.x >> 6);
    int lane = threadIdx.x & 63;
    if (node >= N_NODES) return;
    int beg = rowptr[node], end = rowptr[node + 1];
    float ad = ald[node];
    float m = -INFINITY;
    for (int i = beg; i < end; ++i) m = fmaxf(m, lrelu(als[csr_src[i]] + ad));
    float den = 0.f, acc = 0.f;
    for (int i = beg; i < end; ++i) {
        int s = csr_src[i];
        float p = expf(lrelu(als[s] + ad) - m);
        den += p;
        if (lane < OUTC) acc += p * hf[(size_t)s * OUTC + lane];
    }
    float r = (lane < OUTC) ? acc / (den + 1e-16f) + b3[lane] : -INFINITY;
    float mx = r;
    #pragma unroll
    for (int off = 32; off; off >>= 1) mx = fmaxf(mx, __shfl_xor(mx, off));
    float ex = (lane < OUTC) ? expf(r - mx) : 0.f;
    float sum = ex;
    #pragma unroll
    for (int off = 32; off; off >>= 1) sum += __shfl_xor(sum, off);
    if (lane < OUTC) out[(size_t)node * OUTC + lane] = r - mx - logf(sum);
}

static inline int cdiv(long long a, long long b) { return (int)((a + b - 1) / b); }

extern "C" void kernel_launch(void* const* d_in, const int* in_sizes, int n_in,
                              void* d_out, int out_size, void* d_ws, size_t ws_size,
                              hipStream_t stream) {
    const float* x   = (const float*)d_in[0];
    const int*   ei  = (const int*)d_in[1];
    const float* W1  = (const float*)d_in[2];
    const float* as1 = (const float*)d_in[3];
    const float* ad1 = (const float*)d_in[4];
    const float* b1  = (const float*)d_in[5];
    const float* W2  = (const float*)d_in[6];
    const float* as2 = (const float*)d_in[7];
    const float* ad2 = (const float*)d_in[8];
    const float* b2  = (const float*)d_in[9];
    const float* W3  = (const float*)d_in[10];
    const float* as3 = (const float*)d_in[11];
    const float* ad3 = (const float*)d_in[12];
    const float* b3  = (const float*)d_in[13];
    float* out = (float*)d_out;

    float* Hb  = (float*)d_ws;                        // [N,512]
    float* Xb  = Hb + (size_t)N_NODES * HH512;        // [N,512]
    float* als = Xb + (size_t)N_NODES * HH512;        // [N,8]
    float* ald = als + (size_t)N_NODES * HEADS;       // [N,8]
    int* rowptr  = (int*)(ald + (size_t)N_NODES * HEADS); // [N+1]
    int* pos     = rowptr + (N_NODES + 1);                // [N]
    int* csr_src = pos + N_NODES;                         // [E_TOT]

    dim3 blk(256);

    // ---- CSR build (dst-sorted incoming edges; reused by all 3 layers) ----
    hipMemsetAsync(pos, 0, (size_t)N_NODES * 4, stream);
    deg_count_k<<<cdiv(E_TOT, 256), blk, 0, stream>>>(ei, pos);
    scan_k<<<1, 1024, 0, stream>>>(pos, rowptr);
    scatter_k<<<cdiv(E_TOT, 256), blk, 0, stream>>>(ei, pos, csr_src);

    // ================= Layer 1 : x[N,256] -> Xb[N,512] =================
    gemm_f32<<<dim3(cdiv(N_NODES, 64), 8), blk, 0, stream>>>(x, W1, Hb, N_NODES, HH512, 256);
    attn_logits_k<<<cdiv((long long)N_NODES * HEADS * 64, 256), blk, 0, stream>>>(Hb, as1, ad1, als, ald, HEADS, 64);
    node_agg8_k<<<cdiv(N_NODES, 4), blk, 0, stream>>>(rowptr, csr_src, als, ald, Hb, b1, Xb);

    // ================= Layer 2 : Xb[N,512] -> Xb[N,512] =================
    gemm_f32<<<dim3(cdiv(N_NODES, 64), 8), blk, 0, stream>>>(Xb, W2, Hb, N_NODES, HH512, HH512);
    attn_logits_k<<<cdiv((long long)N_NODES * HEADS * 64, 256), blk, 0, stream>>>(Hb, as2, ad2, als, ald, HEADS, 64);
    node_agg8_k<<<cdiv(N_NODES, 4), blk, 0, stream>>>(rowptr, csr_src, als, ald, Hb, b2, Xb);

    // ================= Layer 3 : Xb[N,512] -> out[N,47] =================
    gemm_f32<<<dim3(cdiv(N_NODES, 64), 1), blk, 0, stream>>>(Xb, W3, Hb, N_NODES, OUTC, HH512);
    attn_logits_k<<<cdiv((long long)N_NODES * 64, 256), blk, 0, stream>>>(Hb, as3, ad3, als, ald, 1, OUTC);
    node_agg_final_k<<<cdiv(N_NODES, 4), blk, 0, stream>>>(rowptr, csr_src, als, ald, Hb, b3, out);
}

// Round 8
// 1534.153 us; speedup vs baseline: 3.0415x; 1.5342x over previous
//
#include <hip/hip_runtime.h>
#include <math.h>

#define N_NODES 50000
#define N_EDGESX 800000
#define E_TOT   (N_EDGESX + N_NODES)
#define HEADS 8
#define HID 64
#define HH512 (HID*HEADS)     // 512
#define OUTC 47
#define NEG_SLOPE 0.2f

typedef float f32x4 __attribute__((ext_vector_type(4)));
typedef short s16x8 __attribute__((ext_vector_type(8)));   // 8 bf16 (4 VGPRs) per guide §3
typedef short s16x4 __attribute__((ext_vector_type(4)));

__device__ __forceinline__ float lrelu(float x) { return x > 0.f ? x : NEG_SLOPE * x; }

// f32 -> bf16 bits, round-to-nearest-even (finite inputs)
__device__ __forceinline__ short f2bf(float f) {
    unsigned u = __float_as_uint(f);
    unsigned r = (u + 0x7FFFu + ((u >> 16) & 1u)) >> 16;
    return (short)r;
}

// ---------------- bf16 MFMA GEMM: C[M,N](f32) = A[M,K](bf16) * Bt[N,K](bf16) ----------------
#define GBM 128
#define GBN 128
#define GBK 32
#define LDK 40   // padded LDS K-stride: bank step 20 -> 2-way max (free)
__global__ __launch_bounds__(256) void gemm_bf16(const short* __restrict__ A,
                                                 const short* __restrict__ Bt,
                                                 float* __restrict__ C,
                                                 int M, int N, int K) {
    __shared__ short As[GBM][LDK];
    __shared__ short Bs[GBN][LDK];
    int tid = threadIdx.x;
    int lane = tid & 63;
    int wave = tid >> 6;
    int wr = wave >> 1, wc = wave & 1;      // 2x2 wave grid, 64x64 per wave
    int brow = blockIdx.x * GBM, bcol = blockIdx.y * GBN;
    int lr = lane & 15;                      // row/col within 16x16 frag
    int kg = (lane >> 4) * 8;                // k offset within 32
    f32x4 acc[4][4] = {};
    for (int k0 = 0; k0 < K; k0 += GBK) {
        #pragma unroll
        for (int c = tid; c < 512; c += 256) {          // A tile: 128 rows x 32 k
            int row = c >> 2, ko = (c & 3) * 8;
            int gr = brow + row;
            s16x8 v = {};
            if (gr < M) v = *(const s16x8*)&A[(size_t)gr * K + k0 + ko];
            *(s16x8*)&As[row][ko] = v;
        }
        #pragma unroll
        for (int c = tid; c < 512; c += 256) {          // B tile: 128 cols x 32 k
            int col = c >> 2, ko = (c & 3) * 8;
            int gc = bcol + col;
            s16x8 v = {};
            if (gc < N) v = *(const s16x8*)&Bt[(size_t)gc * K + k0 + ko];
            *(s16x8*)&Bs[col][ko] = v;
        }
        __syncthreads();
        s16x8 af[4], bfr[4];
        #pragma unroll
        for (int m = 0; m < 4; ++m) af[m] = *(const s16x8*)&As[wr * 64 + m * 16 + lr][kg];
        #pragma unroll
        for (int n = 0; n < 4; ++n) bfr[n] = *(const s16x8*)&Bs[wc * 64 + n * 16 + lr][kg];
        #pragma unroll
        for (int m = 0; m < 4; ++m)
            #pragma unroll
            for (int n = 0; n < 4; ++n)
                acc[m][n] = __builtin_amdgcn_mfma_f32_16x16x32_bf16(af[m], bfr[n], acc[m][n], 0, 0, 0);
        __syncthreads();
    }
    // C/D layout: col = lane&15, row = (lane>>4)*4 + i   [guide §3, m89-verified]
    int r4 = (lane >> 4) * 4;
    #pragma unroll
    for (int m = 0; m < 4; ++m) {
        #pragma unroll
        for (int n = 0; n < 4; ++n) {
            int col = bcol + wc * 64 + n * 16 + lr;
            if (col >= N) continue;
            #pragma unroll
            for (int i = 0; i < 4; ++i) {
                int row = brow + wr * 64 + m * 16 + r4 + i;
                if (row < M) C[(size_t)row * N + col] = acc[m][n][i];
            }
        }
    }
}

// ---------------- casts ----------------
__global__ void cast_bf16_k(const float* __restrict__ in, short* __restrict__ outb, long long n) {
    long long i = ((long long)blockIdx.x * blockDim.x + threadIdx.x) * 4;
    if (i >= n) return;
    float4 f = *(const float4*)(in + i);
    s16x4 o = {f2bf(f.x), f2bf(f.y), f2bf(f.z), f2bf(f.w)};
    *(s16x4*)(outb + i) = o;
}

// W[K][N] f32 -> Wt[N][K] bf16
__global__ void wt_cast_k(const float* __restrict__ W, short* __restrict__ Wt, int K, int N) {
    int t = blockIdx.x * blockDim.x + threadIdx.x;
    if (t >= K * N) return;
    int k = t / N, n = t - k * N;
    Wt[(size_t)n * K + k] = f2bf(W[t]);
}

// ---------------- attention logits: als/ald[n,h] = sum_c h[n,h,c]*a[h,c] ----------------
__global__ void attn_logits_k(const float* __restrict__ h, const float* __restrict__ a_s,
                              const float* __restrict__ a_d, float* __restrict__ als,
                              float* __restrict__ ald, int HH, int C) {
    int t = blockIdx.x * blockDim.x + threadIdx.x;
    int wid = t >> 6, lane = threadIdx.x & 63;
    if (wid >= N_NODES * HH) return;
    int n = wid / HH, hh = wid % HH;
    float hv = (lane < C) ? h[(size_t)n * HH * C + hh * C + lane] : 0.f;
    float vs = (lane < C) ? hv * a_s[hh * C + lane] : 0.f;
    float vd = (lane < C) ? hv * a_d[hh * C + lane] : 0.f;
    #pragma unroll
    for (int off = 32; off; off >>= 1) {
        vs += __shfl_down(vs, off);
        vd += __shfl_down(vd, off);
    }
    if (lane == 0) { als[wid] = vs; ald[wid] = vd; }
}

// ---------------- CSR build ----------------
__global__ void deg_count_k(const int* __restrict__ ei, int* __restrict__ deg) {
    int e = blockIdx.x * blockDim.x + threadIdx.x;
    if (e >= E_TOT) return;
    int d = (e < N_EDGESX) ? ei[N_EDGESX + e] : e - N_EDGESX;
    atomicAdd(&deg[d], 1);
}

__global__ __launch_bounds__(1024) void scan_k(int* __restrict__ pos, int* __restrict__ rowptr) {
    __shared__ int buf[1024];
    __shared__ int carry;
    if (threadIdx.x == 0) carry = 0;
    __syncthreads();
    for (int base = 0; base < N_NODES; base += 1024) {
        int i = base + threadIdx.x;
        int v = (i < N_NODES) ? pos[i] : 0;
        buf[threadIdx.x] = v;
        __syncthreads();
        for (int off = 1; off < 1024; off <<= 1) {
            int t = (threadIdx.x >= off) ? buf[threadIdx.x - off] : 0;
            __syncthreads();
            buf[threadIdx.x] += t;
            __syncthreads();
        }
        int excl = buf[threadIdx.x] - v + carry;
        if (i < N_NODES) { rowptr[i] = excl; pos[i] = excl; }
        __syncthreads();
        if (threadIdx.x == 1023) carry += buf[1023];
        __syncthreads();
    }
    if (threadIdx.x == 0) rowptr[N_NODES] = carry;
}

__global__ void scatter_k(const int* __restrict__ ei, int* __restrict__ pos,
                          int* __restrict__ csr_src) {
    int e = blockIdx.x * blockDim.x + threadIdx.x;
    if (e >= E_TOT) return;
    int s, d;
    if (e < N_EDGESX) { s = ei[e]; d = ei[N_EDGESX + e]; }
    else              { s = e - N_EDGESX; d = s; }
    int idx = atomicAdd(&pos[d], 1);
    csr_src[idx] = s;
}

// ---------------- fused per-node softmax + aggregate, H=8, C=64 (+bias+ReLU), bf16 out ----------------
__global__ __launch_bounds__(256) void node_agg8_k(
    const int* __restrict__ rowptr, const int* __restrict__ csr_src,
    const float* __restrict__ als, const float* __restrict__ ald,
    const float* __restrict__ hf, const float* __restrict__ bias,
    short* __restrict__ out) {
    int node = (blockIdx.x << 2) + (threadIdx.x >> 6);
    int lane = threadIdx.x & 63;
    if (node >= N_NODES) return;
    int beg = rowptr[node], end = rowptr[node + 1];
    float4 d0 = *(const float4*)(ald + (size_t)node * 8);
    float4 d1 = *(const float4*)(ald + (size_t)node * 8 + 4);
    float adv[8] = {d0.x, d0.y, d0.z, d0.w, d1.x, d1.y, d1.z, d1.w};
    float m[8];
    #pragma unroll
    for (int j = 0; j < 8; ++j) m[j] = -INFINITY;
    for (int i = beg; i < end; ++i) {
        int s = csr_src[i];
        float4 s0 = *(const float4*)(als + (size_t)s * 8);
        float4 s1 = *(const float4*)(als + (size_t)s * 8 + 4);
        float sv[8] = {s0.x, s0.y, s0.z, s0.w, s1.x, s1.y, s1.z, s1.w};
        #pragma unroll
        for (int j = 0; j < 8; ++j) m[j] = fmaxf(m[j], lrelu(sv[j] + adv[j]));
    }
    float den[8] = {}, acc[8] = {};
    for (int i = beg; i < end; ++i) {
        int s = csr_src[i];
        float4 s0 = *(const float4*)(als + (size_t)s * 8);
        float4 s1 = *(const float4*)(als + (size_t)s * 8 + 4);
        float sv[8] = {s0.x, s0.y, s0.z, s0.w, s1.x, s1.y, s1.z, s1.w};
        const float* hrow = hf + (size_t)s * HH512;
        #pragma unroll
        for (int j = 0; j < 8; ++j) {
            float p = expf(lrelu(sv[j] + adv[j]) - m[j]);
            den[j] += p;
            acc[j] += p * hrow[j * 64 + lane];
        }
    }
    size_t ob = (size_t)node * HH512;
    #pragma unroll
    for (int j = 0; j < 8; ++j) {
        float r = acc[j] / (den[j] + 1e-16f) + bias[j * 64 + lane];
        out[ob + j * 64 + lane] = f2bf(fmaxf(r, 0.f));
    }
}

// ---------------- final layer: H=1, C=47, fused bias + log_softmax ----------------
__global__ __launch_bounds__(256) void node_agg_final_k(
    const int* __restrict__ rowptr, const int* __restrict__ csr_src,
    const float* __restrict__ als, const float* __restrict__ ald,
    const float* __restrict__ hf, const float* __restrict__ b3,
    float* __restrict__ out) {
    int node = (blockIdx.x << 2) + (threadIdx.x >> 6);
    int lane = threadIdx.x & 63;
    if (node >= N_NODES) return;
    int beg = rowptr[node], end = rowptr[node + 1];
    float ad = ald[node];
    float m = -INFINITY;
    for (int i = beg; i < end; ++i) m = fmaxf(m, lrelu(als[csr_src[i]] + ad));
    float den = 0.f, acc = 0.f;
    for (int i = beg; i < end; ++i) {
        int s = csr_src[i];
        float p = expf(lrelu(als[s] + ad) - m);
        den += p;
        if (lane < OUTC) acc += p * hf[(size_t)s * OUTC + lane];
    }
    float r = (lane < OUTC) ? acc / (den + 1e-16f) + b3[lane] : -INFINITY;
    float mx = r;
    #pragma unroll
    for (int off = 32; off; off >>= 1) mx = fmaxf(mx, __shfl_xor(mx, off));
    float ex = (lane < OUTC) ? expf(r - mx) : 0.f;
    float sum = ex;
    #pragma unroll
    for (int off = 32; off; off >>= 1) sum += __shfl_xor(sum, off);
    if (lane < OUTC) out[(size_t)node * OUTC + lane] = r - mx - logf(sum);
}

static inline int cdiv(long long a, long long b) { return (int)((a + b - 1) / b); }

extern "C" void kernel_launch(void* const* d_in, const int* in_sizes, int n_in,
                              void* d_out, int out_size, void* d_ws, size_t ws_size,
                              hipStream_t stream) {
    const float* x   = (const float*)d_in[0];
    const int*   ei  = (const int*)d_in[1];
    const float* W1  = (const float*)d_in[2];
    const float* as1 = (const float*)d_in[3];
    const float* ad1 = (const float*)d_in[4];
    const float* b1  = (const float*)d_in[5];
    const float* W2  = (const float*)d_in[6];
    const float* as2 = (const float*)d_in[7];
    const float* ad2 = (const float*)d_in[8];
    const float* b2  = (const float*)d_in[9];
    const float* W3  = (const float*)d_in[10];
    const float* as3 = (const float*)d_in[11];
    const float* ad3 = (const float*)d_in[12];
    const float* b3  = (const float*)d_in[13];
    float* out = (float*)d_out;

    short* Abf = (short*)d_ws;                            // [N,512] bf16 (layer1 uses [N,256])
    float* Hb  = (float*)(Abf + (size_t)N_NODES * HH512); // [N,512] f32
    float* als = Hb + (size_t)N_NODES * HH512;            // [N,8]
    float* ald = als + (size_t)N_NODES * HEADS;           // [N,8]
    short* Wt  = (short*)(ald + (size_t)N_NODES * HEADS); // [512,512] bf16 (reused per layer)
    int* rowptr  = (int*)(Wt + (size_t)HH512 * HH512);    // [N+1]
    int* pos     = rowptr + (N_NODES + 1);                // [N]
    int* csr_src = pos + N_NODES;                         // [E_TOT]

    dim3 blk(256);

    // ---- CSR build (dst-sorted incoming edges; reused by all 3 layers) ----
    hipMemsetAsync(pos, 0, (size_t)N_NODES * 4, stream);
    deg_count_k<<<cdiv(E_TOT, 256), blk, 0, stream>>>(ei, pos);
    scan_k<<<1, 1024, 0, stream>>>(pos, rowptr);
    scatter_k<<<cdiv(E_TOT, 256), blk, 0, stream>>>(ei, pos, csr_src);

    // ================= Layer 1 : x[N,256] -> Abf[N,512] =================
    cast_bf16_k<<<cdiv((long long)N_NODES * 256 / 4, 256), blk, 0, stream>>>(x, Abf, (long long)N_NODES * 256);
    wt_cast_k<<<cdiv(256 * HH512, 256), blk, 0, stream>>>(W1, Wt, 256, HH512);
    gemm_bf16<<<dim3(cdiv(N_NODES, GBM), HH512 / GBN), blk, 0, stream>>>(Abf, Wt, Hb, N_NODES, HH512, 256);
    attn_logits_k<<<cdiv((long long)N_NODES * HEADS * 64, 256), blk, 0, stream>>>(Hb, as1, ad1, als, ald, HEADS, 64);
    node_agg8_k<<<cdiv(N_NODES, 4), blk, 0, stream>>>(rowptr, csr_src, als, ald, Hb, b1, Abf);

    // ================= Layer 2 : Abf[N,512] -> Abf[N,512] =================
    wt_cast_k<<<cdiv(HH512 * HH512, 256), blk, 0, stream>>>(W2, Wt, HH512, HH512);
    gemm_bf16<<<dim3(cdiv(N_NODES, GBM), HH512 / GBN), blk, 0, stream>>>(Abf, Wt, Hb, N_NODES, HH512, HH512);
    attn_logits_k<<<cdiv((long long)N_NODES * HEADS * 64, 256), blk, 0, stream>>>(Hb, as2, ad2, als, ald, HEADS, 64);
    node_agg8_k<<<cdiv(N_NODES, 4), blk, 0, stream>>>(rowptr, csr_src, als, ald, Hb, b2, Abf);

    // ================= Layer 3 : Abf[N,512] -> out[N,47] =================
    wt_cast_k<<<cdiv(HH512 * OUTC, 256), blk, 0, stream>>>(W3, Wt, HH512, OUTC);
    gemm_bf16<<<dim3(cdiv(N_NODES, GBM), 1), blk, 0, stream>>>(Abf, Wt, Hb, N_NODES, OUTC, HH512);
    attn_logits_k<<<cdiv((long long)N_NODES * 64, 256), blk, 0, stream>>>(Hb, as3, ad3, als, ald, 1, OUTC);
    node_agg_final_k<<<cdiv(N_NODES, 4), blk, 0, stream>>>(rowptr, csr_src, als, ald, Hb, b3, out);
}

// Round 11
// 962.219 us; speedup vs baseline: 4.8493x; 1.5944x over previous
//
#include <hip/hip_runtime.h>
#include <math.h>

#define N_NODES 50000
#define N_EDGESX 800000
#define E_TOT   (N_EDGESX + N_NODES)
#define HEADS 8
#define HID 64
#define HH512 (HID*HEADS)     // 512
#define OUTC 47
#define NEG_SLOPE 0.2f

typedef float f32x4 __attribute__((ext_vector_type(4)));
typedef short s16x8 __attribute__((ext_vector_type(8)));   // 8 bf16 (4 VGPRs)
typedef short s16x4 __attribute__((ext_vector_type(4)));

__device__ __forceinline__ float lrelu(float x) { return x > 0.f ? x : NEG_SLOPE * x; }

// f32 -> bf16 bits, round-to-nearest-even (finite inputs)
__device__ __forceinline__ short f2bf(float f) {
    unsigned u = __float_as_uint(f);
    unsigned r = (u + 0x7FFFu + ((u >> 16) & 1u)) >> 16;
    return (short)r;
}
__device__ __forceinline__ float bf2f(unsigned short b) {
    return __uint_as_float(((unsigned)b) << 16);
}

// ---------------- bf16 MFMA GEMM: C[M,N](bf16) = A[M,K](bf16) * Bt[N,K](bf16) ----------------
#define GBM 128
#define GBN 128
#define GBK 32
#define LDK 40   // padded LDS K-stride: bank step 20 -> 2-way max (free)
__global__ __launch_bounds__(256) void gemm_bf16(const short* __restrict__ A,
                                                 const short* __restrict__ Bt,
                                                 unsigned short* __restrict__ C,
                                                 int M, int N, int K) {
    __shared__ short As[GBM][LDK];
    __shared__ short Bs[GBN][LDK];
    int tid = threadIdx.x;
    int lane = tid & 63;
    int wave = tid >> 6;
    int wr = wave >> 1, wc = wave & 1;      // 2x2 wave grid, 64x64 per wave
    int brow = blockIdx.x * GBM, bcol = blockIdx.y * GBN;
    int lr = lane & 15;
    int kg = (lane >> 4) * 8;
    f32x4 acc[4][4] = {};
    for (int k0 = 0; k0 < K; k0 += GBK) {
        #pragma unroll
        for (int c = tid; c < 512; c += 256) {
            int row = c >> 2, ko = (c & 3) * 8;
            int gr = brow + row;
            s16x8 v = {};
            if (gr < M) v = *(const s16x8*)&A[(size_t)gr * K + k0 + ko];
            *(s16x8*)&As[row][ko] = v;
        }
        #pragma unroll
        for (int c = tid; c < 512; c += 256) {
            int col = c >> 2, ko = (c & 3) * 8;
            int gc = bcol + col;
            s16x8 v = {};
            if (gc < N) v = *(const s16x8*)&Bt[(size_t)gc * K + k0 + ko];
            *(s16x8*)&Bs[col][ko] = v;
        }
        __syncthreads();
        s16x8 af[4], bfr[4];
        #pragma unroll
        for (int m = 0; m < 4; ++m) af[m] = *(const s16x8*)&As[wr * 64 + m * 16 + lr][kg];
        #pragma unroll
        for (int n = 0; n < 4; ++n) bfr[n] = *(const s16x8*)&Bs[wc * 64 + n * 16 + lr][kg];
        #pragma unroll
        for (int m = 0; m < 4; ++m)
            #pragma unroll
            for (int n = 0; n < 4; ++n)
                acc[m][n] = __builtin_amdgcn_mfma_f32_16x16x32_bf16(af[m], bfr[n], acc[m][n], 0, 0, 0);
        __syncthreads();
    }
    int r4 = (lane >> 4) * 4;   // C/D: col = lane&15, row = (lane>>4)*4 + i
    #pragma unroll
    for (int m = 0; m < 4; ++m) {
        #pragma unroll
        for (int n = 0; n < 4; ++n) {
            int col = bcol + wc * 64 + n * 16 + lr;
            if (col >= N) continue;
            #pragma unroll
            for (int i = 0; i < 4; ++i) {
                int row = brow + wr * 64 + m * 16 + r4 + i;
                if (row < M) C[(size_t)row * N + col] = (unsigned short)f2bf(acc[m][n][i]);
            }
        }
    }
}

// ---------------- casts ----------------
__global__ void cast_bf16_k(const float* __restrict__ in, short* __restrict__ outb, long long n) {
    long long i = ((long long)blockIdx.x * blockDim.x + threadIdx.x) * 4;
    if (i >= n) return;
    float4 f = *(const float4*)(in + i);
    s16x4 o = {f2bf(f.x), f2bf(f.y), f2bf(f.z), f2bf(f.w)};
    *(s16x4*)(outb + i) = o;
}

// W[K][N] f32 -> Wt[N][K] bf16
__global__ void wt_cast_k(const float* __restrict__ W, short* __restrict__ Wt, int K, int N) {
    int t = blockIdx.x * blockDim.x + threadIdx.x;
    if (t >= K * N) return;
    int k = t / N, n = t - k * N;
    Wt[(size_t)n * K + k] = f2bf(W[t]);
}

// ---------------- attention logits from bf16 h ----------------
__global__ void attn_logits_k(const unsigned short* __restrict__ h, const float* __restrict__ a_s,
                              const float* __restrict__ a_d, float* __restrict__ als,
                              float* __restrict__ ald, int HH, int C) {
    int t = blockIdx.x * blockDim.x + threadIdx.x;
    int wid = t >> 6, lane = threadIdx.x & 63;
    if (wid >= N_NODES * HH) return;
    int n = wid / HH, hh = wid % HH;
    float hv = (lane < C) ? bf2f(h[(size_t)n * HH * C + hh * C + lane]) : 0.f;
    float vs = (lane < C) ? hv * a_s[hh * C + lane] : 0.f;
    float vd = (lane < C) ? hv * a_d[hh * C + lane] : 0.f;
    #pragma unroll
    for (int off = 32; off; off >>= 1) {
        vs += __shfl_down(vs, off);
        vd += __shfl_down(vd, off);
    }
    if (lane == 0) { als[wid] = vs; ald[wid] = vd; }
}

// ---------------- CSR build ----------------
__global__ void deg_count_k(const int* __restrict__ ei, int* __restrict__ deg) {
    int e = blockIdx.x * blockDim.x + threadIdx.x;
    if (e >= E_TOT) return;
    int d = (e < N_EDGESX) ? ei[N_EDGESX + e] : e - N_EDGESX;
    atomicAdd(&deg[d], 1);
}

__global__ __launch_bounds__(1024) void scan_k(int* __restrict__ pos, int* __restrict__ rowptr) {
    __shared__ int buf[1024];
    __shared__ int carry;
    if (threadIdx.x == 0) carry = 0;
    __syncthreads();
    for (int base = 0; base < N_NODES; base += 1024) {
        int i = base + threadIdx.x;
        int v = (i < N_NODES) ? pos[i] : 0;
        buf[threadIdx.x] = v;
        __syncthreads();
        for (int off = 1; off < 1024; off <<= 1) {
            int t = (threadIdx.x >= off) ? buf[threadIdx.x - off] : 0;
            __syncthreads();
            buf[threadIdx.x] += t;
            __syncthreads();
        }
        int excl = buf[threadIdx.x] - v + carry;
        if (i < N_NODES) { rowptr[i] = excl; pos[i] = excl; }
        __syncthreads();
        if (threadIdx.x == 1023) carry += buf[1023];
        __syncthreads();
    }
    if (threadIdx.x == 0) rowptr[N_NODES] = carry;
}

__global__ void scatter_k(const int* __restrict__ ei, int* __restrict__ pos,
                          int* __restrict__ csr_src) {
    int e = blockIdx.x * blockDim.x + threadIdx.x;
    if (e >= E_TOT) return;
    int s, d;
    if (e < N_EDGESX) { s = ei[e]; d = ei[N_EDGESX + e]; }
    else              { s = e - N_EDGESX; d = s; }
    int idx = atomicAdd(&pos[d], 1);
    csr_src[idx] = s;
}

// ---------------- fused softmax+aggregate, H=8, C=64, wave-parallel softmax ----------------
// lane = (e,h) during softmax phases (e = lane>>3 edge-in-chunk, h = lane&7);
// lane = channel during the FMA phase.
__global__ __launch_bounds__(256) void node_agg8_k(
    const int* __restrict__ rowptr, const int* __restrict__ csr_src,
    const float* __restrict__ als, const float* __restrict__ ald,
    const unsigned short* __restrict__ hb, const float* __restrict__ bias,
    short* __restrict__ out) {
    int node = (blockIdx.x << 2) + (threadIdx.x >> 6);
    int lane = threadIdx.x & 63;
    if (node >= N_NODES) return;
    int beg = rowptr[node], end = rowptr[node + 1];
    int eh_e = lane >> 3, eh_h = lane & 7;
    float adv = ald[(size_t)node * 8 + eh_h];
    // pass 1: m[h] — each lane maxes over its (e,h) slice, then reduce over e bits
    float vmax = -INFINITY;
    for (int c0 = beg; c0 < end; c0 += 8) {
        int i = c0 + eh_e;
        int s = csr_src[i < end ? i : (end - 1)];
        float v = lrelu(als[(size_t)s * 8 + eh_h] + adv);
        if (i < end) vmax = fmaxf(vmax, v);
    }
    vmax = fmaxf(vmax, __shfl_xor(vmax, 8));
    vmax = fmaxf(vmax, __shfl_xor(vmax, 16));
    vmax = fmaxf(vmax, __shfl_xor(vmax, 32));   // vmax = m[lane&7], uniform across e-groups
    // pass 2: p per (e,h) lane; broadcast to 64-channel FMA
    float den = 0.f;
    float acc[8] = {};
    for (int c0 = beg; c0 < end; c0 += 8) {
        int i = c0 + eh_e;
        bool valid = (i < end);
        int s = csr_src[valid ? i : beg];
        float v = lrelu(als[(size_t)s * 8 + eh_h] + adv);
        float p = valid ? expf(v - vmax) : 0.f;
        den += p;
        #pragma unroll
        for (int e = 0; e < 8; ++e) {
            if (c0 + e >= end) break;                    // uniform across wave
            int se = __shfl(s, e * 8);
            const unsigned short* hrow = hb + (size_t)se * HH512;
            #pragma unroll
            for (int j = 0; j < 8; ++j) {
                float pj = __shfl(p, e * 8 + j);
                acc[j] += pj * bf2f(hrow[j * 64 + lane]);
            }
        }
    }
    den += __shfl_xor(den, 8);
    den += __shfl_xor(den, 16);
    den += __shfl_xor(den, 32);                          // den = den[lane&7]
    size_t ob = (size_t)node * HH512;
    #pragma unroll
    for (int j = 0; j < 8; ++j) {
        float dj = __shfl(den, j);                       // lane j holds den[h=j]
        float r = acc[j] / (dj + 1e-16f) + bias[j * 64 + lane];
        out[ob + j * 64 + lane] = f2bf(fmaxf(r, 0.f));
    }
}

// ---------------- final layer: H=1, C=47, bf16 h, fused bias + log_softmax ----------------
__global__ __launch_bounds__(256) void node_agg_final_k(
    const int* __restrict__ rowptr, const int* __restrict__ csr_src,
    const float* __restrict__ als, const float* __restrict__ ald,
    const unsigned short* __restrict__ hb, const float* __restrict__ b3,
    float* __restrict__ out) {
    int node = (blockIdx.x << 2) + (threadIdx.x >> 6);
    int lane = threadIdx.x & 63;
    if (node >= N_NODES) return;
    int beg = rowptr[node], end = rowptr[node + 1];
    float ad = ald[node];
    float m = -INFINITY;
    for (int i = beg; i < end; ++i) m = fmaxf(m, lrelu(als[csr_src[i]] + ad));
    float den = 0.f, acc = 0.f;
    for (int i = beg; i < end; ++i) {
        int s = csr_src[i];
        float p = expf(lrelu(als[s] + ad) - m);
        den += p;
        if (lane < OUTC) acc += p * bf2f(hb[(size_t)s * OUTC + lane]);
    }
    float r = (lane < OUTC) ? acc / (den + 1e-16f) + b3[lane] : -INFINITY;
    float mx = r;
    #pragma unroll
    for (int off = 32; off; off >>= 1) mx = fmaxf(mx, __shfl_xor(mx, off));
    float ex = (lane < OUTC) ? expf(r - mx) : 0.f;
    float sum = ex;
    #pragma unroll
    for (int off = 32; off; off >>= 1) sum += __shfl_xor(sum, off);
    if (lane < OUTC) out[(size_t)node * OUTC + lane] = r - mx - logf(sum);
}

static inline int cdiv(long long a, long long b) { return (int)((a + b - 1) / b); }

extern "C" void kernel_launch(void* const* d_in, const int* in_sizes, int n_in,
                              void* d_out, int out_size, void* d_ws, size_t ws_size,
                              hipStream_t stream) {
    const float* x   = (const float*)d_in[0];
    const int*   ei  = (const int*)d_in[1];
    const float* W1  = (const float*)d_in[2];
    const float* as1 = (const float*)d_in[3];
    const float* ad1 = (const float*)d_in[4];
    const float* b1  = (const float*)d_in[5];
    const float* W2  = (const float*)d_in[6];
    const float* as2 = (const float*)d_in[7];
    const float* ad2 = (const float*)d_in[8];
    const float* b2  = (const float*)d_in[9];
    const float* W3  = (const float*)d_in[10];
    const float* as3 = (const float*)d_in[11];
    const float* ad3 = (const float*)d_in[12];
    const float* b3  = (const float*)d_in[13];
    float* out = (float*)d_out;

    short* Abf = (short*)d_ws;                                     // [N,512] bf16
    unsigned short* Hb = (unsigned short*)(Abf + (size_t)N_NODES * HH512); // [N,512] bf16
    float* als = (float*)(Hb + (size_t)N_NODES * HH512);           // [N,8]
    float* ald = als + (size_t)N_NODES * HEADS;                    // [N,8]
    short* Wt  = (short*)(ald + (size_t)N_NODES * HEADS);          // [512,512] bf16
    int* rowptr  = (int*)(Wt + (size_t)HH512 * HH512);             // [N+1]
    int* pos     = rowptr + (N_NODES + 1);                         // [N]
    int* csr_src = pos + N_NODES;                                  // [E_TOT]

    dim3 blk(256);

    // ---- CSR build (reused by all 3 layers) ----
    hipMemsetAsync(pos, 0, (size_t)N_NODES * 4, stream);
    deg_count_k<<<cdiv(E_TOT, 256), blk, 0, stream>>>(ei, pos);
    scan_k<<<1, 1024, 0, stream>>>(pos, rowptr);
    scatter_k<<<cdiv(E_TOT, 256), blk, 0, stream>>>(ei, pos, csr_src);

    // ================= Layer 1 =================
    cast_bf16_k<<<cdiv((long long)N_NODES * 256 / 4, 256), blk, 0, stream>>>(x, Abf, (long long)N_NODES * 256);
    wt_cast_k<<<cdiv(256 * HH512, 256), blk, 0, stream>>>(W1, Wt, 256, HH512);
    gemm_bf16<<<dim3(cdiv(N_NODES, GBM), HH512 / GBN), blk, 0, stream>>>(Abf, Wt, Hb, N_NODES, HH512, 256);
    attn_logits_k<<<cdiv((long long)N_NODES * HEADS * 64, 256), blk, 0, stream>>>(Hb, as1, ad1, als, ald, HEADS, 64);
    node_agg8_k<<<cdiv(N_NODES, 4), blk, 0, stream>>>(rowptr, csr_src, als, ald, Hb, b1, Abf);

    // ================= Layer 2 =================
    wt_cast_k<<<cdiv(HH512 * HH512, 256), blk, 0, stream>>>(W2, Wt, HH512, HH512);
    gemm_bf16<<<dim3(cdiv(N_NODES, GBM), HH512 / GBN), blk, 0, stream>>>(Abf, Wt, Hb, N_NODES, HH512, HH512);
    attn_logits_k<<<cdiv((long long)N_NODES * HEADS * 64, 256), blk, 0, stream>>>(Hb, as2, ad2, als, ald, HEADS, 64);
    node_agg8_k<<<cdiv(N_NODES, 4), blk, 0, stream>>>(rowptr, csr_src, als, ald, Hb, b2, Abf);

    // ================= Layer 3 =================
    wt_cast_k<<<cdiv(HH512 * OUTC, 256), blk, 0, stream>>>(W3, Wt, HH512, OUTC);
    gemm_bf16<<<dim3(cdiv(N_NODES, GBM), 1), blk, 0, stream>>>(Abf, Wt, Hb, N_NODES, OUTC, HH512);
    attn_logits_k<<<cdiv((long long)N_NODES * 64, 256), blk, 0, stream>>>(Hb, as3, ad3, als, ald, 1, OUTC);
    node_agg_final_k<<<cdiv(N_NODES, 4), blk, 0, stream>>>(rowptr, csr_src, als, ald, Hb, b3, out);
}

// Round 12
// 850.139 us; speedup vs baseline: 5.4886x; 1.1318x over previous
//
#include <hip/hip_runtime.h>
#include <math.h>

#define N_NODES 50000
#define N_EDGESX 800000
#define E_TOT   (N_EDGESX + N_NODES)
#define HEADS 8
#define HID 64
#define HH512 (HID*HEADS)     // 512
#define OUTC 47
#define NEG_SLOPE 0.2f

typedef float f32x4 __attribute__((ext_vector_type(4)));
typedef short s16x8 __attribute__((ext_vector_type(8)));   // 8 bf16 (4 VGPRs)
typedef short s16x4 __attribute__((ext_vector_type(4)));

__device__ __forceinline__ float lrelu(float x) { return x > 0.f ? x : NEG_SLOPE * x; }

// f32 -> bf16 bits, round-to-nearest-even (finite inputs)
__device__ __forceinline__ short f2bf(float f) {
    unsigned u = __float_as_uint(f);
    unsigned r = (u + 0x7FFFu + ((u >> 16) & 1u)) >> 16;
    return (short)r;
}
__device__ __forceinline__ float bf2f(unsigned short b) {
    return __uint_as_float(((unsigned)b) << 16);
}

// ---------------- bf16 MFMA GEMM: C[M,N](bf16) = A[M,K](bf16) * Bt[N,K](bf16) ----------------
#define GBM 128
#define GBN 128
#define GBK 32
#define LDK 40   // padded LDS K-stride: bank step 20 -> 2-way max (free)
__global__ __launch_bounds__(256) void gemm_bf16(const short* __restrict__ A,
                                                 const short* __restrict__ Bt,
                                                 unsigned short* __restrict__ C,
                                                 int M, int N, int K) {
    __shared__ short As[GBM][LDK];
    __shared__ short Bs[GBN][LDK];
    int tid = threadIdx.x;
    int lane = tid & 63;
    int wave = tid >> 6;
    int wr = wave >> 1, wc = wave & 1;      // 2x2 wave grid, 64x64 per wave
    int brow = blockIdx.x * GBM, bcol = blockIdx.y * GBN;
    int lr = lane & 15;
    int kg = (lane >> 4) * 8;
    f32x4 acc[4][4] = {};
    for (int k0 = 0; k0 < K; k0 += GBK) {
        #pragma unroll
        for (int c = tid; c < 512; c += 256) {
            int row = c >> 2, ko = (c & 3) * 8;
            int gr = brow + row;
            s16x8 v = {};
            if (gr < M) v = *(const s16x8*)&A[(size_t)gr * K + k0 + ko];
            *(s16x8*)&As[row][ko] = v;
        }
        #pragma unroll
        for (int c = tid; c < 512; c += 256) {
            int col = c >> 2, ko = (c & 3) * 8;
            int gc = bcol + col;
            s16x8 v = {};
            if (gc < N) v = *(const s16x8*)&Bt[(size_t)gc * K + k0 + ko];
            *(s16x8*)&Bs[col][ko] = v;
        }
        __syncthreads();
        s16x8 af[4], bfr[4];
        #pragma unroll
        for (int m = 0; m < 4; ++m) af[m] = *(const s16x8*)&As[wr * 64 + m * 16 + lr][kg];
        #pragma unroll
        for (int n = 0; n < 4; ++n) bfr[n] = *(const s16x8*)&Bs[wc * 64 + n * 16 + lr][kg];
        #pragma unroll
        for (int m = 0; m < 4; ++m)
            #pragma unroll
            for (int n = 0; n < 4; ++n)
                acc[m][n] = __builtin_amdgcn_mfma_f32_16x16x32_bf16(af[m], bfr[n], acc[m][n], 0, 0, 0);
        __syncthreads();
    }
    int r4 = (lane >> 4) * 4;   // C/D: col = lane&15, row = (lane>>4)*4 + i
    #pragma unroll
    for (int m = 0; m < 4; ++m) {
        #pragma unroll
        for (int n = 0; n < 4; ++n) {
            int col = bcol + wc * 64 + n * 16 + lr;
            if (col >= N) continue;
            #pragma unroll
            for (int i = 0; i < 4; ++i) {
                int row = brow + wr * 64 + m * 16 + r4 + i;
                if (row < M) C[(size_t)row * N + col] = (unsigned short)f2bf(acc[m][n][i]);
            }
        }
    }
}

// ---------------- casts ----------------
__global__ void cast_bf16_k(const float* __restrict__ in, short* __restrict__ outb, long long n) {
    long long i = ((long long)blockIdx.x * blockDim.x + threadIdx.x) * 4;
    if (i >= n) return;
    float4 f = *(const float4*)(in + i);
    s16x4 o = {f2bf(f.x), f2bf(f.y), f2bf(f.z), f2bf(f.w)};
    *(s16x4*)(outb + i) = o;
}

// W[K][N] f32 -> Wt[N][K] bf16
__global__ void wt_cast_k(const float* __restrict__ W, short* __restrict__ Wt, int K, int N) {
    int t = blockIdx.x * blockDim.x + threadIdx.x;
    if (t >= K * N) return;
    int k = t / N, n = t - k * N;
    Wt[(size_t)n * K + k] = f2bf(W[t]);
}

// ---------------- attention logits from bf16 h ----------------
__global__ void attn_logits_k(const unsigned short* __restrict__ h, const float* __restrict__ a_s,
                              const float* __restrict__ a_d, float* __restrict__ als,
                              float* __restrict__ ald, int HH, int C) {
    int t = blockIdx.x * blockDim.x + threadIdx.x;
    int wid = t >> 6, lane = threadIdx.x & 63;
    if (wid >= N_NODES * HH) return;
    int n = wid / HH, hh = wid % HH;
    float hv = (lane < C) ? bf2f(h[(size_t)n * HH * C + hh * C + lane]) : 0.f;
    float vs = (lane < C) ? hv * a_s[hh * C + lane] : 0.f;
    float vd = (lane < C) ? hv * a_d[hh * C + lane] : 0.f;
    #pragma unroll
    for (int off = 32; off; off >>= 1) {
        vs += __shfl_down(vs, off);
        vd += __shfl_down(vd, off);
    }
    if (lane == 0) { als[wid] = vs; ald[wid] = vd; }
}

// ---------------- CSR build ----------------
__global__ void deg_count_k(const int* __restrict__ ei, int* __restrict__ deg) {
    int e = blockIdx.x * blockDim.x + threadIdx.x;
    if (e >= E_TOT) return;
    int d = (e < N_EDGESX) ? ei[N_EDGESX + e] : e - N_EDGESX;
    atomicAdd(&deg[d], 1);
}

// shuffle-based scan: 2 barriers per 1024-chunk (was ~20)
__global__ __launch_bounds__(1024) void scan_k(int* __restrict__ pos, int* __restrict__ rowptr) {
    __shared__ int wsum[16];
    __shared__ int carry_s;
    int tid = threadIdx.x, lane = tid & 63, w = tid >> 6;
    if (tid == 0) carry_s = 0;
    __syncthreads();
    for (int base = 0; base < N_NODES; base += 1024) {
        int i = base + tid;
        int v = (i < N_NODES) ? pos[i] : 0;
        int sc = v;                                   // inclusive wave scan
        #pragma unroll
        for (int off = 1; off < 64; off <<= 1) {
            int t = __shfl_up(sc, off);
            if (lane >= off) sc += t;
        }
        if (lane == 63) wsum[w] = sc;
        __syncthreads();
        if (w == 0 && lane < 16) {
            int s = wsum[lane];                       // inclusive scan of 16 wave sums
            #pragma unroll
            for (int off = 1; off < 16; off <<= 1) {
                int t = __shfl_up(s, off);
                if (lane >= off) s += t;
            }
            wsum[lane] = s;
        }
        __syncthreads();
        int wbase = (w > 0) ? wsum[w - 1] : 0;
        int excl = carry_s + wbase + sc - v;
        if (i < N_NODES) { rowptr[i] = excl; pos[i] = excl; }
        __syncthreads();                              // all reads of carry_s done
        if (tid == 1023) carry_s += wsum[15];
        __syncthreads();
    }
    if (threadIdx.x == 0) rowptr[N_NODES] = carry_s;
}

__global__ void scatter_k(const int* __restrict__ ei, int* __restrict__ pos,
                          int* __restrict__ csr_src) {
    int e = blockIdx.x * blockDim.x + threadIdx.x;
    if (e >= E_TOT) return;
    int s, d;
    if (e < N_EDGESX) { s = ei[e]; d = ei[N_EDGESX + e]; }
    else              { s = e - N_EDGESX; d = s; }
    int idx = atomicAdd(&pos[d], 1);
    csr_src[idx] = s;
}

// ---------------- fused softmax+aggregate, H=8, C=64, wave-parallel softmax ----------------
__global__ __launch_bounds__(256) void node_agg8_k(
    const int* __restrict__ rowptr, const int* __restrict__ csr_src,
    const float* __restrict__ als, const float* __restrict__ ald,
    const unsigned short* __restrict__ hb, const float* __restrict__ bias,
    short* __restrict__ out) {
    int node = (blockIdx.x << 2) + (threadIdx.x >> 6);
    int lane = threadIdx.x & 63;
    if (node >= N_NODES) return;
    int beg = rowptr[node], end = rowptr[node + 1];
    int eh_e = lane >> 3, eh_h = lane & 7;
    float adv = ald[(size_t)node * 8 + eh_h];
    float vmax = -INFINITY;
    for (int c0 = beg; c0 < end; c0 += 8) {
        int i = c0 + eh_e;
        int s = csr_src[i < end ? i : (end - 1)];
        float v = lrelu(als[(size_t)s * 8 + eh_h] + adv);
        if (i < end) vmax = fmaxf(vmax, v);
    }
    vmax = fmaxf(vmax, __shfl_xor(vmax, 8));
    vmax = fmaxf(vmax, __shfl_xor(vmax, 16));
    vmax = fmaxf(vmax, __shfl_xor(vmax, 32));
    float den = 0.f;
    float acc[8] = {};
    for (int c0 = beg; c0 < end; c0 += 8) {
        int i = c0 + eh_e;
        bool valid = (i < end);
        int s = csr_src[valid ? i : beg];
        float v = lrelu(als[(size_t)s * 8 + eh_h] + adv);
        float p = valid ? expf(v - vmax) : 0.f;
        den += p;
        #pragma unroll
        for (int e = 0; e < 8; ++e) {
            if (c0 + e >= end) break;                    // uniform across wave
            int se = __shfl(s, e * 8);
            const unsigned short* hrow = hb + (size_t)se * HH512;
            #pragma unroll
            for (int j = 0; j < 8; ++j) {
                float pj = __shfl(p, e * 8 + j);
                acc[j] += pj * bf2f(hrow[j * 64 + lane]);
            }
        }
    }
    den += __shfl_xor(den, 8);
    den += __shfl_xor(den, 16);
    den += __shfl_xor(den, 32);
    size_t ob = (size_t)node * HH512;
    #pragma unroll
    for (int j = 0; j < 8; ++j) {
        float dj = __shfl(den, j);
        float r = acc[j] / (dj + 1e-16f) + bias[j * 64 + lane];
        out[ob + j * 64 + lane] = f2bf(fmaxf(r, 0.f));
    }
}

// ---------------- final layer: H=1, C=47, wave-parallel softmax + bias + log_softmax ----------------
__global__ __launch_bounds__(256) void node_agg_final_k(
    const int* __restrict__ rowptr, const int* __restrict__ csr_src,
    const float* __restrict__ als, const float* __restrict__ ald,
    const unsigned short* __restrict__ hb, const float* __restrict__ b3,
    float* __restrict__ out) {
    int node = (blockIdx.x << 2) + (threadIdx.x >> 6);
    int lane = threadIdx.x & 63;
    if (node >= N_NODES) return;
    int beg = rowptr[node], end = rowptr[node + 1];
    float ad = ald[node];
    // pass 1: lane-parallel max over edges
    float vmax = -INFINITY;
    for (int i = beg + lane; i < end; i += 64)
        vmax = fmaxf(vmax, lrelu(als[csr_src[i]] + ad));
    #pragma unroll
    for (int off = 32; off; off >>= 1) vmax = fmaxf(vmax, __shfl_xor(vmax, off));
    // pass 2: lane=edge alphas, shuffle-broadcast into 47-channel FMA
    float den = 0.f, acc = 0.f;
    for (int c0 = beg; c0 < end; c0 += 64) {
        int i = c0 + lane;
        bool valid = (i < end);
        int s = csr_src[valid ? i : beg];
        float p = valid ? expf(lrelu(als[s] + ad) - vmax) : 0.f;
        den += p;
        #pragma unroll 4
        for (int e = 0; e < 64; ++e) {
            if (c0 + e >= end) break;                    // uniform across wave
            int se = __shfl(s, e);
            float pe = __shfl(p, e);
            if (lane < OUTC) acc += pe * bf2f(hb[(size_t)se * OUTC + lane]);
        }
    }
    #pragma unroll
    for (int off = 32; off; off >>= 1) den += __shfl_xor(den, off);
    float r = (lane < OUTC) ? acc / (den + 1e-16f) + b3[lane] : -INFINITY;
    float mx = r;
    #pragma unroll
    for (int off = 32; off; off >>= 1) mx = fmaxf(mx, __shfl_xor(mx, off));
    float ex = (lane < OUTC) ? expf(r - mx) : 0.f;
    float sum = ex;
    #pragma unroll
    for (int off = 32; off; off >>= 1) sum += __shfl_xor(sum, off);
    if (lane < OUTC) out[(size_t)node * OUTC + lane] = r - mx - logf(sum);
}

static inline int cdiv(long long a, long long b) { return (int)((a + b - 1) / b); }

extern "C" void kernel_launch(void* const* d_in, const int* in_sizes, int n_in,
                              void* d_out, int out_size, void* d_ws, size_t ws_size,
                              hipStream_t stream) {
    const float* x   = (const float*)d_in[0];
    const int*   ei  = (const int*)d_in[1];
    const float* W1  = (const float*)d_in[2];
    const float* as1 = (const float*)d_in[3];
    const float* ad1 = (const float*)d_in[4];
    const float* b1  = (const float*)d_in[5];
    const float* W2  = (const float*)d_in[6];
    const float* as2 = (const float*)d_in[7];
    const float* ad2 = (const float*)d_in[8];
    const float* b2  = (const float*)d_in[9];
    const float* W3  = (const float*)d_in[10];
    const float* as3 = (const float*)d_in[11];
    const float* ad3 = (const float*)d_in[12];
    const float* b3  = (const float*)d_in[13];
    float* out = (float*)d_out;

    short* Abf = (short*)d_ws;                                     // [N,512] bf16
    unsigned short* Hb = (unsigned short*)(Abf + (size_t)N_NODES * HH512); // [N,512] bf16
    float* als = (float*)(Hb + (size_t)N_NODES * HH512);           // [N,8]
    float* ald = als + (size_t)N_NODES * HEADS;                    // [N,8]
    short* Wt  = (short*)(ald + (size_t)N_NODES * HEADS);          // [512,512] bf16
    int* rowptr  = (int*)(Wt + (size_t)HH512 * HH512);             // [N+1]
    int* pos     = rowptr + (N_NODES + 1);                         // [N]
    int* csr_src = pos + N_NODES;                                  // [E_TOT]

    dim3 blk(256);

    // ---- CSR build (reused by all 3 layers) ----
    hipMemsetAsync(pos, 0, (size_t)N_NODES * 4, stream);
    deg_count_k<<<cdiv(E_TOT, 256), blk, 0, stream>>>(ei, pos);
    scan_k<<<1, 1024, 0, stream>>>(pos, rowptr);
    scatter_k<<<cdiv(E_TOT, 256), blk, 0, stream>>>(ei, pos, csr_src);

    // ================= Layer 1 =================
    cast_bf16_k<<<cdiv((long long)N_NODES * 256 / 4, 256), blk, 0, stream>>>(x, Abf, (long long)N_NODES * 256);
    wt_cast_k<<<cdiv(256 * HH512, 256), blk, 0, stream>>>(W1, Wt, 256, HH512);
    gemm_bf16<<<dim3(cdiv(N_NODES, GBM), HH512 / GBN), blk, 0, stream>>>(Abf, Wt, Hb, N_NODES, HH512, 256);
    attn_logits_k<<<cdiv((long long)N_NODES * HEADS * 64, 256), blk, 0, stream>>>(Hb, as1, ad1, als, ald, HEADS, 64);
    node_agg8_k<<<cdiv(N_NODES, 4), blk, 0, stream>>>(rowptr, csr_src, als, ald, Hb, b1, Abf);

    // ================= Layer 2 =================
    wt_cast_k<<<cdiv(HH512 * HH512, 256), blk, 0, stream>>>(W2, Wt, HH512, HH512);
    gemm_bf16<<<dim3(cdiv(N_NODES, GBM), HH512 / GBN), blk, 0, stream>>>(Abf, Wt, Hb, N_NODES, HH512, HH512);
    attn_logits_k<<<cdiv((long long)N_NODES * HEADS * 64, 256), blk, 0, stream>>>(Hb, as2, ad2, als, ald, HEADS, 64);
    node_agg8_k<<<cdiv(N_NODES, 4), blk, 0, stream>>>(rowptr, csr_src, als, ald, Hb, b2, Abf);

    // ================= Layer 3 =================
    wt_cast_k<<<cdiv(HH512 * OUTC, 256), blk, 0, stream>>>(W3, Wt, HH512, OUTC);
    gemm_bf16<<<dim3(cdiv(N_NODES, GBM), 1), blk, 0, stream>>>(Abf, Wt, Hb, N_NODES, OUTC, HH512);
    attn_logits_k<<<cdiv((long long)N_NODES * 64, 256), blk, 0, stream>>>(Hb, as3, ad3, als, ald, 1, OUTC);
    node_agg_final_k<<<cdiv(N_NODES, 4), blk, 0, stream>>>(rowptr, csr_src, als, ald, Hb, b3, out);
}

// Round 13
// 839.002 us; speedup vs baseline: 5.5615x; 1.0133x over previous
//
#include <hip/hip_runtime.h>
#include <math.h>

#define N_NODES 50000
#define N_EDGESX 800000
#define E_TOT   (N_EDGESX + N_NODES)
#define HEADS 8
#define HID 64
#define HH512 (HID*HEADS)     // 512
#define OUTC 47
#define NEG_SLOPE 0.2f

typedef float f32x4 __attribute__((ext_vector_type(4)));
typedef short s16x8 __attribute__((ext_vector_type(8)));   // 8 bf16 (4 VGPRs)
typedef short s16x4 __attribute__((ext_vector_type(4)));

__device__ __forceinline__ float lrelu(float x) { return x > 0.f ? x : NEG_SLOPE * x; }

// f32 -> bf16 bits, round-to-nearest-even (finite inputs)
__device__ __forceinline__ short f2bf(float f) {
    unsigned u = __float_as_uint(f);
    unsigned r = (u + 0x7FFFu + ((u >> 16) & 1u)) >> 16;
    return (short)r;
}
__device__ __forceinline__ float bf2f(unsigned short b) {
    return __uint_as_float(((unsigned)b) << 16);
}

// ---------------- bf16 MFMA GEMM: C[M,N](bf16) = A[M,K](bf16) * Bt[N,K](bf16) ----------------
#define GBM 128
#define GBN 128
#define GBK 32
#define LDK 40   // padded LDS K-stride: bank step 20 -> 2-way max (free)
__global__ __launch_bounds__(256) void gemm_bf16(const short* __restrict__ A,
                                                 const short* __restrict__ Bt,
                                                 unsigned short* __restrict__ C,
                                                 int M, int N, int K) {
    __shared__ short As[GBM][LDK];
    __shared__ short Bs[GBN][LDK];
    int tid = threadIdx.x;
    int lane = tid & 63;
    int wave = tid >> 6;
    int wr = wave >> 1, wc = wave & 1;      // 2x2 wave grid, 64x64 per wave
    int brow = blockIdx.x * GBM, bcol = blockIdx.y * GBN;
    int lr = lane & 15;
    int kg = (lane >> 4) * 8;
    f32x4 acc[4][4] = {};
    for (int k0 = 0; k0 < K; k0 += GBK) {
        #pragma unroll
        for (int c = tid; c < 512; c += 256) {
            int row = c >> 2, ko = (c & 3) * 8;
            int gr = brow + row;
            s16x8 v = {};
            if (gr < M) v = *(const s16x8*)&A[(size_t)gr * K + k0 + ko];
            *(s16x8*)&As[row][ko] = v;
        }
        #pragma unroll
        for (int c = tid; c < 512; c += 256) {
            int col = c >> 2, ko = (c & 3) * 8;
            int gc = bcol + col;
            s16x8 v = {};
            if (gc < N) v = *(const s16x8*)&Bt[(size_t)gc * K + k0 + ko];
            *(s16x8*)&Bs[col][ko] = v;
        }
        __syncthreads();
        s16x8 af[4], bfr[4];
        #pragma unroll
        for (int m = 0; m < 4; ++m) af[m] = *(const s16x8*)&As[wr * 64 + m * 16 + lr][kg];
        #pragma unroll
        for (int n = 0; n < 4; ++n) bfr[n] = *(const s16x8*)&Bs[wc * 64 + n * 16 + lr][kg];
        #pragma unroll
        for (int m = 0; m < 4; ++m)
            #pragma unroll
            for (int n = 0; n < 4; ++n)
                acc[m][n] = __builtin_amdgcn_mfma_f32_16x16x32_bf16(af[m], bfr[n], acc[m][n], 0, 0, 0);
        __syncthreads();
    }
    int r4 = (lane >> 4) * 4;   // C/D: col = lane&15, row = (lane>>4)*4 + i
    #pragma unroll
    for (int m = 0; m < 4; ++m) {
        #pragma unroll
        for (int n = 0; n < 4; ++n) {
            int col = bcol + wc * 64 + n * 16 + lr;
            if (col >= N) continue;
            #pragma unroll
            for (int i = 0; i < 4; ++i) {
                int row = brow + wr * 64 + m * 16 + r4 + i;
                if (row < M) C[(size_t)row * N + col] = (unsigned short)f2bf(acc[m][n][i]);
            }
        }
    }
}

// ---------------- casts ----------------
__global__ void cast_bf16_k(const float* __restrict__ in, short* __restrict__ outb, long long n) {
    long long i = ((long long)blockIdx.x * blockDim.x + threadIdx.x) * 4;
    if (i >= n) return;
    float4 f = *(const float4*)(in + i);
    s16x4 o = {f2bf(f.x), f2bf(f.y), f2bf(f.z), f2bf(f.w)};
    *(s16x4*)(outb + i) = o;
}

// W[K][N] f32 -> Wt[nn][kk] bf16 with optional head-interleave permutations:
// il(i) = (i&63)*8 + (i>>6)  (for 512-sized dims)
__global__ void wt_cast_k(const float* __restrict__ W, short* __restrict__ Wt, int K, int N,
                          int ilk, int iln) {
    int t = blockIdx.x * blockDim.x + threadIdx.x;
    if (t >= K * N) return;
    int k = t / N, n = t - k * N;
    int kk = ilk ? ((k & 63) * 8 + (k >> 6)) : k;
    int nn = iln ? ((n & 63) * 8 + (n >> 6)) : n;
    Wt[(size_t)nn * K + kk] = f2bf(W[t]);
}

// ---------------- attention logits, interleaved h [n][c][h], HH=8 C=64 ----------------
__global__ void attn_logits_il_k(const unsigned short* __restrict__ h, const float* __restrict__ a_s,
                                 const float* __restrict__ a_d, float* __restrict__ als,
                                 float* __restrict__ ald) {
    int t = blockIdx.x * blockDim.x + threadIdx.x;
    int wid = t >> 6, lane = threadIdx.x & 63;
    if (wid >= N_NODES * 8) return;
    int n = wid >> 3, hh = wid & 7;
    float hv = bf2f(h[(size_t)n * HH512 + lane * 8 + hh]);
    float vs = hv * a_s[hh * 64 + lane];
    float vd = hv * a_d[hh * 64 + lane];
    #pragma unroll
    for (int off = 32; off; off >>= 1) {
        vs += __shfl_down(vs, off);
        vd += __shfl_down(vd, off);
    }
    if (lane == 0) { als[wid] = vs; ald[wid] = vd; }
}

// ---------------- attention logits, plain h [n][C] (final layer HH=1 C=47) ----------------
__global__ void attn_logits_k(const unsigned short* __restrict__ h, const float* __restrict__ a_s,
                              const float* __restrict__ a_d, float* __restrict__ als,
                              float* __restrict__ ald, int C) {
    int t = blockIdx.x * blockDim.x + threadIdx.x;
    int wid = t >> 6, lane = threadIdx.x & 63;
    if (wid >= N_NODES) return;
    float hv = (lane < C) ? bf2f(h[(size_t)wid * C + lane]) : 0.f;
    float vs = (lane < C) ? hv * a_s[lane] : 0.f;
    float vd = (lane < C) ? hv * a_d[lane] : 0.f;
    #pragma unroll
    for (int off = 32; off; off >>= 1) {
        vs += __shfl_down(vs, off);
        vd += __shfl_down(vd, off);
    }
    if (lane == 0) { als[wid] = vs; ald[wid] = vd; }
}

// ---------------- CSR build ----------------
__global__ void deg_count_k(const int* __restrict__ ei, int* __restrict__ deg) {
    int e = blockIdx.x * blockDim.x + threadIdx.x;
    if (e >= E_TOT) return;
    int d = (e < N_EDGESX) ? ei[N_EDGESX + e] : e - N_EDGESX;
    atomicAdd(&deg[d], 1);
}

// shuffle-based scan: 2 barriers per 1024-chunk
__global__ __launch_bounds__(1024) void scan_k(int* __restrict__ pos, int* __restrict__ rowptr) {
    __shared__ int wsum[16];
    __shared__ int carry_s;
    int tid = threadIdx.x, lane = tid & 63, w = tid >> 6;
    if (tid == 0) carry_s = 0;
    __syncthreads();
    for (int base = 0; base < N_NODES; base += 1024) {
        int i = base + tid;
        int v = (i < N_NODES) ? pos[i] : 0;
        int sc = v;
        #pragma unroll
        for (int off = 1; off < 64; off <<= 1) {
            int t = __shfl_up(sc, off);
            if (lane >= off) sc += t;
        }
        if (lane == 63) wsum[w] = sc;
        __syncthreads();
        if (w == 0 && lane < 16) {
            int s = wsum[lane];
            #pragma unroll
            for (int off = 1; off < 16; off <<= 1) {
                int t = __shfl_up(s, off);
                if (lane >= off) s += t;
            }
            wsum[lane] = s;
        }
        __syncthreads();
        int wbase = (w > 0) ? wsum[w - 1] : 0;
        int excl = carry_s + wbase + sc - v;
        if (i < N_NODES) { rowptr[i] = excl; pos[i] = excl; }
        __syncthreads();
        if (tid == 1023) carry_s += wsum[15];
        __syncthreads();
    }
    if (threadIdx.x == 0) rowptr[N_NODES] = carry_s;
}

__global__ void scatter_k(const int* __restrict__ ei, int* __restrict__ pos,
                          int* __restrict__ csr_src) {
    int e = blockIdx.x * blockDim.x + threadIdx.x;
    if (e >= E_TOT) return;
    int s, d;
    if (e < N_EDGESX) { s = ei[e]; d = ei[N_EDGESX + e]; }
    else              { s = e - N_EDGESX; d = s; }
    int idx = atomicAdd(&pos[d], 1);
    csr_src[idx] = s;
}

// ---------------- fused softmax+aggregate, interleaved h/out, wave-parallel softmax ----------------
__global__ __launch_bounds__(256) void node_agg8_k(
    const int* __restrict__ rowptr, const int* __restrict__ csr_src,
    const float* __restrict__ als, const float* __restrict__ ald,
    const unsigned short* __restrict__ hb, const float* __restrict__ bias,
    short* __restrict__ out) {
    int node = (blockIdx.x << 2) + (threadIdx.x >> 6);
    int lane = threadIdx.x & 63;
    if (node >= N_NODES) return;
    int beg = rowptr[node], end = rowptr[node + 1];
    int eh_e = lane >> 3, eh_h = lane & 7;
    float adv = ald[(size_t)node * 8 + eh_h];
    float vmax = -INFINITY;
    for (int c0 = beg; c0 < end; c0 += 8) {
        int i = c0 + eh_e;
        int s = csr_src[i < end ? i : (end - 1)];
        float v = lrelu(als[(size_t)s * 8 + eh_h] + adv);
        if (i < end) vmax = fmaxf(vmax, v);
    }
    vmax = fmaxf(vmax, __shfl_xor(vmax, 8));
    vmax = fmaxf(vmax, __shfl_xor(vmax, 16));
    vmax = fmaxf(vmax, __shfl_xor(vmax, 32));
    float den = 0.f;
    float acc[8] = {};
    for (int c0 = beg; c0 < end; c0 += 8) {
        int i = c0 + eh_e;
        bool valid = (i < end);
        int s = csr_src[valid ? i : beg];
        float v = lrelu(als[(size_t)s * 8 + eh_h] + adv);
        float p = valid ? expf(v - vmax) : 0.f;
        den += p;
        #pragma unroll
        for (int e = 0; e < 8; ++e) {
            if (c0 + e >= end) break;                    // uniform across wave
            int se = __shfl(s, e * 8);
            s16x8 hv = *(const s16x8*)(hb + (size_t)se * HH512 + lane * 8);  // 16B coalesced
            #pragma unroll
            for (int j = 0; j < 8; ++j) {
                float pj = __shfl(p, e * 8 + j);
                acc[j] += pj * bf2f((unsigned short)hv[j]);
            }
        }
    }
    den += __shfl_xor(den, 8);
    den += __shfl_xor(den, 16);
    den += __shfl_xor(den, 32);
    s16x8 ov;
    #pragma unroll
    for (int j = 0; j < 8; ++j) {
        float dj = __shfl(den, j);                       // lane j holds den[h=j]
        float r = acc[j] / (dj + 1e-16f) + bias[j * 64 + lane];
        ov[j] = f2bf(fmaxf(r, 0.f));
    }
    *(s16x8*)(out + (size_t)node * HH512 + lane * 8) = ov;  // 16B vector store
}

// ---------------- final layer: H=1, C=47, wave-parallel softmax + bias + log_softmax ----------------
__global__ __launch_bounds__(256) void node_agg_final_k(
    const int* __restrict__ rowptr, const int* __restrict__ csr_src,
    const float* __restrict__ als, const float* __restrict__ ald,
    const unsigned short* __restrict__ hb, const float* __restrict__ b3,
    float* __restrict__ out) {
    int node = (blockIdx.x << 2) + (threadIdx.x >> 6);
    int lane = threadIdx.x & 63;
    if (node >= N_NODES) return;
    int beg = rowptr[node], end = rowptr[node + 1];
    float ad = ald[node];
    float vmax = -INFINITY;
    for (int i = beg + lane; i < end; i += 64)
        vmax = fmaxf(vmax, lrelu(als[csr_src[i]] + ad));
    #pragma unroll
    for (int off = 32; off; off >>= 1) vmax = fmaxf(vmax, __shfl_xor(vmax, off));
    float den = 0.f, acc = 0.f;
    for (int c0 = beg; c0 < end; c0 += 64) {
        int i = c0 + lane;
        bool valid = (i < end);
        int s = csr_src[valid ? i : beg];
        float p = valid ? expf(lrelu(als[s] + ad) - vmax) : 0.f;
        den += p;
        #pragma unroll 4
        for (int e = 0; e < 64; ++e) {
            if (c0 + e >= end) break;                    // uniform across wave
            int se = __shfl(s, e);
            float pe = __shfl(p, e);
            if (lane < OUTC) acc += pe * bf2f(hb[(size_t)se * OUTC + lane]);
        }
    }
    #pragma unroll
    for (int off = 32; off; off >>= 1) den += __shfl_xor(den, off);
    float r = (lane < OUTC) ? acc / (den + 1e-16f) + b3[lane] : -INFINITY;
    float mx = r;
    #pragma unroll
    for (int off = 32; off; off >>= 1) mx = fmaxf(mx, __shfl_xor(mx, off));
    float ex = (lane < OUTC) ? expf(r - mx) : 0.f;
    float sum = ex;
    #pragma unroll
    for (int off = 32; off; off >>= 1) sum += __shfl_xor(sum, off);
    if (lane < OUTC) out[(size_t)node * OUTC + lane] = r - mx - logf(sum);
}

static inline int cdiv(long long a, long long b) { return (int)((a + b - 1) / b); }

extern "C" void kernel_launch(void* const* d_in, const int* in_sizes, int n_in,
                              void* d_out, int out_size, void* d_ws, size_t ws_size,
                              hipStream_t stream) {
    const float* x   = (const float*)d_in[0];
    const int*   ei  = (const int*)d_in[1];
    const float* W1  = (const float*)d_in[2];
    const float* as1 = (const float*)d_in[3];
    const float* ad1 = (const float*)d_in[4];
    const float* b1  = (const float*)d_in[5];
    const float* W2  = (const float*)d_in[6];
    const float* as2 = (const float*)d_in[7];
    const float* ad2 = (const float*)d_in[8];
    const float* b2  = (const float*)d_in[9];
    const float* W3  = (const float*)d_in[10];
    const float* as3 = (const float*)d_in[11];
    const float* ad3 = (const float*)d_in[12];
    const float* b3  = (const float*)d_in[13];
    float* out = (float*)d_out;

    short* Abf = (short*)d_ws;                                     // [N,512] bf16 (interleaved)
    unsigned short* Hb = (unsigned short*)(Abf + (size_t)N_NODES * HH512); // [N,512] bf16 (interleaved)
    float* als = (float*)(Hb + (size_t)N_NODES * HH512);           // [N,8]
    float* ald = als + (size_t)N_NODES * HEADS;                    // [N,8]
    short* Wt  = (short*)(ald + (size_t)N_NODES * HEADS);          // [512,512] bf16
    int* rowptr  = (int*)(Wt + (size_t)HH512 * HH512);             // [N+1]
    int* pos     = rowptr + (N_NODES + 1);                         // [N]
    int* csr_src = pos + N_NODES;                                  // [E_TOT]

    dim3 blk(256);

    // ---- CSR build (reused by all 3 layers) ----
    hipMemsetAsync(pos, 0, (size_t)N_NODES * 4, stream);
    deg_count_k<<<cdiv(E_TOT, 256), blk, 0, stream>>>(ei, pos);
    scan_k<<<1, 1024, 0, stream>>>(pos, rowptr);
    scatter_k<<<cdiv(E_TOT, 256), blk, 0, stream>>>(ei, pos, csr_src);

    // ================= Layer 1 : x plain -> Hb interleaved =================
    cast_bf16_k<<<cdiv((long long)N_NODES * 256 / 4, 256), blk, 0, stream>>>(x, Abf, (long long)N_NODES * 256);
    wt_cast_k<<<cdiv(256 * HH512, 256), blk, 0, stream>>>(W1, Wt, 256, HH512, 0, 1);
    gemm_bf16<<<dim3(cdiv(N_NODES, GBM), HH512 / GBN), blk, 0, stream>>>(Abf, Wt, Hb, N_NODES, HH512, 256);
    attn_logits_il_k<<<cdiv((long long)N_NODES * HEADS * 64, 256), blk, 0, stream>>>(Hb, as1, ad1, als, ald);
    node_agg8_k<<<cdiv(N_NODES, 4), blk, 0, stream>>>(rowptr, csr_src, als, ald, Hb, b1, Abf);

    // ================= Layer 2 : interleaved -> interleaved =================
    wt_cast_k<<<cdiv(HH512 * HH512, 256), blk, 0, stream>>>(W2, Wt, HH512, HH512, 1, 1);
    gemm_bf16<<<dim3(cdiv(N_NODES, GBM), HH512 / GBN), blk, 0, stream>>>(Abf, Wt, Hb, N_NODES, HH512, HH512);
    attn_logits_il_k<<<cdiv((long long)N_NODES * HEADS * 64, 256), blk, 0, stream>>>(Hb, as2, ad2, als, ald);
    node_agg8_k<<<cdiv(N_NODES, 4), blk, 0, stream>>>(rowptr, csr_src, als, ald, Hb, b2, Abf);

    // ================= Layer 3 : interleaved -> plain [N,47] =================
    wt_cast_k<<<cdiv(HH512 * OUTC, 256), blk, 0, stream>>>(W3, Wt, HH512, OUTC, 1, 0);
    gemm_bf16<<<dim3(cdiv(N_NODES, GBM), 1), blk, 0, stream>>>(Abf, Wt, Hb, N_NODES, OUTC, HH512);
    attn_logits_k<<<cdiv((long long)N_NODES * 64, 256), blk, 0, stream>>>(Hb, as3, ad3, als, ald, OUTC);
    node_agg_final_k<<<cdiv(N_NODES, 4), blk, 0, stream>>>(rowptr, csr_src, als, ald, Hb, b3, out);
}

// Round 14
// 716.101 us; speedup vs baseline: 6.5160x; 1.1716x over previous
//
#include <hip/hip_runtime.h>
#include <math.h>

#define N_NODES 50000
#define N_EDGESX 800000
#define E_TOT   (N_EDGESX + N_NODES)
#define HEADS 8
#define HID 64
#define HH512 (HID*HEADS)     // 512
#define OUTC 47
#define NEG_SLOPE 0.2f

typedef float f32x4 __attribute__((ext_vector_type(4)));
typedef short s16x8 __attribute__((ext_vector_type(8)));   // 8 bf16 (4 VGPRs)
typedef short s16x4 __attribute__((ext_vector_type(4)));

__device__ __forceinline__ float lrelu(float x) { return x > 0.f ? x : NEG_SLOPE * x; }

// f32 -> bf16 bits, round-to-nearest-even (finite inputs)
__device__ __forceinline__ short f2bf(float f) {
    unsigned u = __float_as_uint(f);
    unsigned r = (u + 0x7FFFu + ((u >> 16) & 1u)) >> 16;
    return (short)r;
}
__device__ __forceinline__ float bf2f(unsigned short b) {
    return __uint_as_float(((unsigned)b) << 16);
}

// ---------------- bf16 MFMA GEMM + fused attention-logit epilogue ----------------
// C[M,N](bf16) = A[M,K](bf16) * Bt[N,K](bf16); als/ald[n,h] = sum_c h*a  (f32, from acc)
// logitC: 64 (8 heads, head = col/64) or 47 (1 head, cols 0..46). alsp==nullptr -> no fuse.
#define GBM 128
#define GBN 128
#define GBK 32
#define LDK 40   // padded LDS K-stride: bank step 20 -> 2-way max (free)
__global__ __launch_bounds__(256) void gemm_bf16(const short* __restrict__ A,
                                                 const short* __restrict__ Bt,
                                                 unsigned short* __restrict__ C,
                                                 int M, int N, int K,
                                                 const float* __restrict__ a_s,
                                                 const float* __restrict__ a_d,
                                                 float* __restrict__ alsp,
                                                 float* __restrict__ aldp,
                                                 int logitC, int nheads) {
    __shared__ short As[GBM][LDK];
    __shared__ short Bs[GBN][LDK];
    int tid = threadIdx.x;
    int lane = tid & 63;
    int wave = tid >> 6;
    int wr = wave >> 1, wc = wave & 1;      // 2x2 wave grid, 64x64 per wave
    int brow = blockIdx.x * GBM, bcol = blockIdx.y * GBN;
    int lr = lane & 15;
    int kg = (lane >> 4) * 8;
    f32x4 acc[4][4] = {};
    for (int k0 = 0; k0 < K; k0 += GBK) {
        #pragma unroll
        for (int c = tid; c < 512; c += 256) {
            int row = c >> 2, ko = (c & 3) * 8;
            int gr = brow + row;
            s16x8 v = {};
            if (gr < M) v = *(const s16x8*)&A[(size_t)gr * K + k0 + ko];
            *(s16x8*)&As[row][ko] = v;
        }
        #pragma unroll
        for (int c = tid; c < 512; c += 256) {
            int col = c >> 2, ko = (c & 3) * 8;
            int gc = bcol + col;
            s16x8 v = {};
            if (gc < N) v = *(const s16x8*)&Bt[(size_t)gc * K + k0 + ko];
            *(s16x8*)&Bs[col][ko] = v;
        }
        __syncthreads();
        s16x8 af[4], bfr[4];
        #pragma unroll
        for (int m = 0; m < 4; ++m) af[m] = *(const s16x8*)&As[wr * 64 + m * 16 + lr][kg];
        #pragma unroll
        for (int n = 0; n < 4; ++n) bfr[n] = *(const s16x8*)&Bs[wc * 64 + n * 16 + lr][kg];
        #pragma unroll
        for (int m = 0; m < 4; ++m)
            #pragma unroll
            for (int n = 0; n < 4; ++n)
                acc[m][n] = __builtin_amdgcn_mfma_f32_16x16x32_bf16(af[m], bfr[n], acc[m][n], 0, 0, 0);
        __syncthreads();
    }
    int r4 = (lane >> 4) * 4;   // C/D: col = lane&15, row = (lane>>4)*4 + i
    #pragma unroll
    for (int m = 0; m < 4; ++m) {
        #pragma unroll
        for (int n = 0; n < 4; ++n) {
            int col = bcol + wc * 64 + n * 16 + lr;
            if (col >= N) continue;
            #pragma unroll
            for (int i = 0; i < 4; ++i) {
                int row = brow + wr * 64 + m * 16 + r4 + i;
                if (row < M) C[(size_t)row * N + col] = (unsigned short)f2bf(acc[m][n][i]);
            }
        }
    }
    // ---- fused logits: wave (wr,wc) owns rows [brow+wr*64, +64) x head (bcol+wc*64)/64 ----
    if (alsp) {
        int colbase = bcol + wc * 64;
        bool active = (logitC == 64) || (colbase == 0);
        if (active) {
            int h = (logitC == 64) ? (colbase >> 6) : 0;
            float asr[4], adr[4];
            #pragma unroll
            for (int n = 0; n < 4; ++n) {
                int c = n * 16 + lr;
                asr[n] = (c < logitC) ? a_s[h * logitC + c] : 0.f;
                adr[n] = (c < logitC) ? a_d[h * logitC + c] : 0.f;
            }
            #pragma unroll
            for (int m = 0; m < 4; ++m) {
                #pragma unroll
                for (int i = 0; i < 4; ++i) {
                    float vs = 0.f, vd = 0.f;
                    #pragma unroll
                    for (int n = 0; n < 4; ++n) {
                        vs += acc[m][n][i] * asr[n];
                        vd += acc[m][n][i] * adr[n];
                    }
                    #pragma unroll
                    for (int off = 1; off < 16; off <<= 1) {
                        vs += __shfl_xor(vs, off);
                        vd += __shfl_xor(vd, off);
                    }
                    int row = brow + wr * 64 + m * 16 + r4 + i;
                    if (lr == 0 && row < M) {
                        alsp[(size_t)row * nheads + h] = vs;
                        aldp[(size_t)row * nheads + h] = vd;
                    }
                }
            }
        }
    }
}

// ---------------- casts ----------------
__global__ void cast_bf16_k(const float* __restrict__ in, short* __restrict__ outb, long long n) {
    long long i = ((long long)blockIdx.x * blockDim.x + threadIdx.x) * 4;
    if (i >= n) return;
    float4 f = *(const float4*)(in + i);
    s16x4 o = {f2bf(f.x), f2bf(f.y), f2bf(f.z), f2bf(f.w)};
    *(s16x4*)(outb + i) = o;
}

// W[K][N] f32 -> Wt[N][K] bf16
__global__ void wt_cast_k(const float* __restrict__ W, short* __restrict__ Wt, int K, int N) {
    int t = blockIdx.x * blockDim.x + threadIdx.x;
    if (t >= K * N) return;
    int k = t / N, n = t - k * N;
    Wt[(size_t)n * K + k] = f2bf(W[t]);
}

// ---------------- CSR build ----------------
__global__ void deg_count_k(const int* __restrict__ ei, int* __restrict__ deg) {
    int e = blockIdx.x * blockDim.x + threadIdx.x;
    if (e >= E_TOT) return;
    int d = (e < N_EDGESX) ? ei[N_EDGESX + e] : e - N_EDGESX;
    atomicAdd(&deg[d], 1);
}

// shuffle-based scan: 2 barriers per 1024-chunk
__global__ __launch_bounds__(1024) void scan_k(int* __restrict__ pos, int* __restrict__ rowptr) {
    __shared__ int wsum[16];
    __shared__ int carry_s;
    int tid = threadIdx.x, lane = tid & 63, w = tid >> 6;
    if (tid == 0) carry_s = 0;
    __syncthreads();
    for (int base = 0; base < N_NODES; base += 1024) {
        int i = base + tid;
        int v = (i < N_NODES) ? pos[i] : 0;
        int sc = v;
        #pragma unroll
        for (int off = 1; off < 64; off <<= 1) {
            int t = __shfl_up(sc, off);
            if (lane >= off) sc += t;
        }
        if (lane == 63) wsum[w] = sc;
        __syncthreads();
        if (w == 0 && lane < 16) {
            int s = wsum[lane];
            #pragma unroll
            for (int off = 1; off < 16; off <<= 1) {
                int t = __shfl_up(s, off);
                if (lane >= off) s += t;
            }
            wsum[lane] = s;
        }
        __syncthreads();
        int wbase = (w > 0) ? wsum[w - 1] : 0;
        int excl = carry_s + wbase + sc - v;
        if (i < N_NODES) { rowptr[i] = excl; pos[i] = excl; }
        __syncthreads();
        if (tid == 1023) carry_s += wsum[15];
        __syncthreads();
    }
    if (threadIdx.x == 0) rowptr[N_NODES] = carry_s;
}

__global__ void scatter_k(const int* __restrict__ ei, int* __restrict__ pos,
                          int* __restrict__ csr_src) {
    int e = blockIdx.x * blockDim.x + threadIdx.x;
    if (e >= E_TOT) return;
    int s, d;
    if (e < N_EDGESX) { s = ei[e]; d = ei[N_EDGESX + e]; }
    else              { s = e - N_EDGESX; d = s; }
    int idx = atomicAdd(&pos[d], 1);
    csr_src[idx] = s;
}

// ---------------- fused softmax+aggregate, H=8, C=64, wave-parallel softmax ----------------
// (plain [n][h][c] h-layout; 8 independent 128B gathers per edge = best measured MLP)
__global__ __launch_bounds__(256) void node_agg8_k(
    const int* __restrict__ rowptr, const int* __restrict__ csr_src,
    const float* __restrict__ als, const float* __restrict__ ald,
    const unsigned short* __restrict__ hb, const float* __restrict__ bias,
    short* __restrict__ out) {
    int node = (blockIdx.x << 2) + (threadIdx.x >> 6);
    int lane = threadIdx.x & 63;
    if (node >= N_NODES) return;
    int beg = rowptr[node], end = rowptr[node + 1];
    int eh_e = lane >> 3, eh_h = lane & 7;
    float adv = ald[(size_t)node * 8 + eh_h];
    float vmax = -INFINITY;
    for (int c0 = beg; c0 < end; c0 += 8) {
        int i = c0 + eh_e;
        int s = csr_src[i < end ? i : (end - 1)];
        float v = lrelu(als[(size_t)s * 8 + eh_h] + adv);
        if (i < end) vmax = fmaxf(vmax, v);
    }
    vmax = fmaxf(vmax, __shfl_xor(vmax, 8));
    vmax = fmaxf(vmax, __shfl_xor(vmax, 16));
    vmax = fmaxf(vmax, __shfl_xor(vmax, 32));
    float den = 0.f;
    float acc[8] = {};
    for (int c0 = beg; c0 < end; c0 += 8) {
        int i = c0 + eh_e;
        bool valid = (i < end);
        int s = csr_src[valid ? i : beg];
        float v = lrelu(als[(size_t)s * 8 + eh_h] + adv);
        float p = valid ? expf(v - vmax) : 0.f;
        den += p;
        #pragma unroll
        for (int e = 0; e < 8; ++e) {
            if (c0 + e >= end) break;                    // uniform across wave
            int se = __shfl(s, e * 8);
            const unsigned short* hrow = hb + (size_t)se * HH512;
            #pragma unroll
            for (int j = 0; j < 8; ++j) {
                float pj = __shfl(p, e * 8 + j);
                acc[j] += pj * bf2f(hrow[j * 64 + lane]);
            }
        }
    }
    den += __shfl_xor(den, 8);
    den += __shfl_xor(den, 16);
    den += __shfl_xor(den, 32);
    size_t ob = (size_t)node * HH512;
    #pragma unroll
    for (int j = 0; j < 8; ++j) {
        float dj = __shfl(den, j);
        float r = acc[j] / (dj + 1e-16f) + bias[j * 64 + lane];
        out[ob + j * 64 + lane] = f2bf(fmaxf(r, 0.f));
    }
}

// ---------------- final layer: H=1, C=47, wave-parallel softmax + bias + log_softmax ----------------
__global__ __launch_bounds__(256) void node_agg_final_k(
    const int* __restrict__ rowptr, const int* __restrict__ csr_src,
    const float* __restrict__ als, const float* __restrict__ ald,
    const unsigned short* __restrict__ hb, const float* __restrict__ b3,
    float* __restrict__ out) {
    int node = (blockIdx.x << 2) + (threadIdx.x >> 6);
    int lane = threadIdx.x & 63;
    if (node >= N_NODES) return;
    int beg = rowptr[node], end = rowptr[node + 1];
    float ad = ald[node];
    float vmax = -INFINITY;
    for (int i = beg + lane; i < end; i += 64)
        vmax = fmaxf(vmax, lrelu(als[csr_src[i]] + ad));
    #pragma unroll
    for (int off = 32; off; off >>= 1) vmax = fmaxf(vmax, __shfl_xor(vmax, off));
    float den = 0.f, acc = 0.f;
    for (int c0 = beg; c0 < end; c0 += 64) {
        int i = c0 + lane;
        bool valid = (i < end);
        int s = csr_src[valid ? i : beg];
        float p = valid ? expf(lrelu(als[s] + ad) - vmax) : 0.f;
        den += p;
        #pragma unroll 4
        for (int e = 0; e < 64; ++e) {
            if (c0 + e >= end) break;                    // uniform across wave
            int se = __shfl(s, e);
            float pe = __shfl(p, e);
            if (lane < OUTC) acc += pe * bf2f(hb[(size_t)se * OUTC + lane]);
        }
    }
    #pragma unroll
    for (int off = 32; off; off >>= 1) den += __shfl_xor(den, off);
    float r = (lane < OUTC) ? acc / (den + 1e-16f) + b3[lane] : -INFINITY;
    float mx = r;
    #pragma unroll
    for (int off = 32; off; off >>= 1) mx = fmaxf(mx, __shfl_xor(mx, off));
    float ex = (lane < OUTC) ? expf(r - mx) : 0.f;
    float sum = ex;
    #pragma unroll
    for (int off = 32; off; off >>= 1) sum += __shfl_xor(sum, off);
    if (lane < OUTC) out[(size_t)node * OUTC + lane] = r - mx - logf(sum);
}

static inline int cdiv(long long a, long long b) { return (int)((a + b - 1) / b); }

extern "C" void kernel_launch(void* const* d_in, const int* in_sizes, int n_in,
                              void* d_out, int out_size, void* d_ws, size_t ws_size,
                              hipStream_t stream) {
    const float* x   = (const float*)d_in[0];
    const int*   ei  = (const int*)d_in[1];
    const float* W1  = (const float*)d_in[2];
    const float* as1 = (const float*)d_in[3];
    const float* ad1 = (const float*)d_in[4];
    const float* b1  = (const float*)d_in[5];
    const float* W2  = (const float*)d_in[6];
    const float* as2 = (const float*)d_in[7];
    const float* ad2 = (const float*)d_in[8];
    const float* b2  = (const float*)d_in[9];
    const float* W3  = (const float*)d_in[10];
    const float* as3 = (const float*)d_in[11];
    const float* ad3 = (const float*)d_in[12];
    const float* b3  = (const float*)d_in[13];
    float* out = (float*)d_out;

    short* Abf = (short*)d_ws;                                     // [N,512] bf16
    unsigned short* Hb = (unsigned short*)(Abf + (size_t)N_NODES * HH512); // [N,512] bf16
    float* als = (float*)(Hb + (size_t)N_NODES * HH512);           // [N,8]
    float* ald = als + (size_t)N_NODES * HEADS;                    // [N,8]
    short* Wt  = (short*)(ald + (size_t)N_NODES * HEADS);          // [512,512] bf16
    int* rowptr  = (int*)(Wt + (size_t)HH512 * HH512);             // [N+1]
    int* pos     = rowptr + (N_NODES + 1);                         // [N]
    int* csr_src = pos + N_NODES;                                  // [E_TOT]

    dim3 blk(256);

    // ---- CSR build (reused by all 3 layers) ----
    hipMemsetAsync(pos, 0, (size_t)N_NODES * 4, stream);
    deg_count_k<<<cdiv(E_TOT, 256), blk, 0, stream>>>(ei, pos);
    scan_k<<<1, 1024, 0, stream>>>(pos, rowptr);
    scatter_k<<<cdiv(E_TOT, 256), blk, 0, stream>>>(ei, pos, csr_src);

    // ================= Layer 1 =================
    cast_bf16_k<<<cdiv((long long)N_NODES * 256 / 4, 256), blk, 0, stream>>>(x, Abf, (long long)N_NODES * 256);
    wt_cast_k<<<cdiv(256 * HH512, 256), blk, 0, stream>>>(W1, Wt, 256, HH512);
    gemm_bf16<<<dim3(cdiv(N_NODES, GBM), HH512 / GBN), blk, 0, stream>>>(
        Abf, Wt, Hb, N_NODES, HH512, 256, as1, ad1, als, ald, 64, HEADS);
    node_agg8_k<<<cdiv(N_NODES, 4), blk, 0, stream>>>(rowptr, csr_src, als, ald, Hb, b1, Abf);

    // ================= Layer 2 =================
    wt_cast_k<<<cdiv(HH512 * HH512, 256), blk, 0, stream>>>(W2, Wt, HH512, HH512);
    gemm_bf16<<<dim3(cdiv(N_NODES, GBM), HH512 / GBN), blk, 0, stream>>>(
        Abf, Wt, Hb, N_NODES, HH512, HH512, as2, ad2, als, ald, 64, HEADS);
    node_agg8_k<<<cdiv(N_NODES, 4), blk, 0, stream>>>(rowptr, csr_src, als, ald, Hb, b2, Abf);

    // ================= Layer 3 =================
    wt_cast_k<<<cdiv(HH512 * OUTC, 256), blk, 0, stream>>>(W3, Wt, HH512, OUTC);
    gemm_bf16<<<dim3(cdiv(N_NODES, GBM), 1), blk, 0, stream>>>(
        Abf, Wt, Hb, N_NODES, OUTC, HH512, as3, ad3, als, ald, 47, 1);
    node_agg_final_k<<<cdiv(N_NODES, 4), blk, 0, stream>>>(rowptr, csr_src, als, ald, Hb, b3, out);
}

// Round 16
// 687.593 us; speedup vs baseline: 6.7861x; 1.0415x over previous
//
#include <hip/hip_runtime.h>
#include <math.h>

#define N_NODES 50000
#define N_EDGESX 800000
#define E_TOT   (N_EDGESX + N_NODES)
#define HEADS 8
#define HID 64
#define HH512 (HID*HEADS)     // 512
#define OUTC 47
#define NEG_SLOPE 0.2f

typedef float f32x4 __attribute__((ext_vector_type(4)));
typedef short s16x8 __attribute__((ext_vector_type(8)));   // 8 bf16 (4 VGPRs)
typedef short s16x4 __attribute__((ext_vector_type(4)));

__device__ __forceinline__ float lrelu(float x) { return x > 0.f ? x : NEG_SLOPE * x; }

// f32 -> bf16 bits, round-to-nearest-even (finite inputs)
__device__ __forceinline__ short f2bf(float f) {
    unsigned u = __float_as_uint(f);
    unsigned r = (u + 0x7FFFu + ((u >> 16) & 1u)) >> 16;
    return (short)r;
}
__device__ __forceinline__ float bf2f(unsigned short b) {
    return __uint_as_float(((unsigned)b) << 16);
}

// ---------------- bf16 MFMA GEMM + fused attention-logit epilogue ----------------
#define GBM 128
#define GBN 128
#define GBK 32
#define LDK 40   // padded LDS K-stride: bank step 20 -> 2-way max (free)
__global__ __launch_bounds__(256) void gemm_bf16(const short* __restrict__ A,
                                                 const short* __restrict__ Bt,
                                                 unsigned short* __restrict__ C,
                                                 int M, int N, int K,
                                                 const float* __restrict__ a_s,
                                                 const float* __restrict__ a_d,
                                                 float* __restrict__ alsp,
                                                 float* __restrict__ aldp,
                                                 int logitC, int nheads) {
    __shared__ short As[GBM][LDK];
    __shared__ short Bs[GBN][LDK];
    int tid = threadIdx.x;
    int lane = tid & 63;
    int wave = tid >> 6;
    int wr = wave >> 1, wc = wave & 1;      // 2x2 wave grid, 64x64 per wave
    int brow = blockIdx.x * GBM, bcol = blockIdx.y * GBN;
    int lr = lane & 15;
    int kg = (lane >> 4) * 8;
    f32x4 acc[4][4] = {};
    for (int k0 = 0; k0 < K; k0 += GBK) {
        #pragma unroll
        for (int c = tid; c < 512; c += 256) {
            int row = c >> 2, ko = (c & 3) * 8;
            int gr = brow + row;
            s16x8 v = {};
            if (gr < M) v = *(const s16x8*)&A[(size_t)gr * K + k0 + ko];
            *(s16x8*)&As[row][ko] = v;
        }
        #pragma unroll
        for (int c = tid; c < 512; c += 256) {
            int col = c >> 2, ko = (c & 3) * 8;
            int gc = bcol + col;
            s16x8 v = {};
            if (gc < N) v = *(const s16x8*)&Bt[(size_t)gc * K + k0 + ko];
            *(s16x8*)&Bs[col][ko] = v;
        }
        __syncthreads();
        s16x8 af[4], bfr[4];
        #pragma unroll
        for (int m = 0; m < 4; ++m) af[m] = *(const s16x8*)&As[wr * 64 + m * 16 + lr][kg];
        #pragma unroll
        for (int n = 0; n < 4; ++n) bfr[n] = *(const s16x8*)&Bs[wc * 64 + n * 16 + lr][kg];
        #pragma unroll
        for (int m = 0; m < 4; ++m)
            #pragma unroll
            for (int n = 0; n < 4; ++n)
                acc[m][n] = __builtin_amdgcn_mfma_f32_16x16x32_bf16(af[m], bfr[n], acc[m][n], 0, 0, 0);
        __syncthreads();
    }
    int r4 = (lane >> 4) * 4;   // C/D: col = lane&15, row = (lane>>4)*4 + i
    #pragma unroll
    for (int m = 0; m < 4; ++m) {
        #pragma unroll
        for (int n = 0; n < 4; ++n) {
            int col = bcol + wc * 64 + n * 16 + lr;
            if (col >= N) continue;
            #pragma unroll
            for (int i = 0; i < 4; ++i) {
                int row = brow + wr * 64 + m * 16 + r4 + i;
                if (row < M) C[(size_t)row * N + col] = (unsigned short)f2bf(acc[m][n][i]);
            }
        }
    }
    // ---- fused logits ----
    if (alsp) {
        int colbase = bcol + wc * 64;
        bool active = (logitC == 64) || (colbase == 0);
        if (active) {
            int h = (logitC == 64) ? (colbase >> 6) : 0;
            float asr[4], adr[4];
            #pragma unroll
            for (int n = 0; n < 4; ++n) {
                int c = n * 16 + lr;
                asr[n] = (c < logitC) ? a_s[h * logitC + c] : 0.f;
                adr[n] = (c < logitC) ? a_d[h * logitC + c] : 0.f;
            }
            #pragma unroll
            for (int m = 0; m < 4; ++m) {
                #pragma unroll
                for (int i = 0; i < 4; ++i) {
                    float vs = 0.f, vd = 0.f;
                    #pragma unroll
                    for (int n = 0; n < 4; ++n) {
                        vs += acc[m][n][i] * asr[n];
                        vd += acc[m][n][i] * adr[n];
                    }
                    #pragma unroll
                    for (int off = 1; off < 16; off <<= 1) {
                        vs += __shfl_xor(vs, off);
                        vd += __shfl_xor(vd, off);
                    }
                    int row = brow + wr * 64 + m * 16 + r4 + i;
                    if (lr == 0 && row < M) {
                        alsp[(size_t)row * nheads + h] = vs;
                        aldp[(size_t)row * nheads + h] = vd;
                    }
                }
            }
        }
    }
}

// ---------------- casts ----------------
__global__ void cast_bf16_k(const float* __restrict__ in, short* __restrict__ outb, long long n) {
    long long i = ((long long)blockIdx.x * blockDim.x + threadIdx.x) * 4;
    if (i >= n) return;
    float4 f = *(const float4*)(in + i);
    s16x4 o = {f2bf(f.x), f2bf(f.y), f2bf(f.z), f2bf(f.w)};
    *(s16x4*)(outb + i) = o;
}

// W[K][N] f32 -> Wt[N][K] bf16
__global__ void wt_cast_k(const float* __restrict__ W, short* __restrict__ Wt, int K, int N) {
    int t = blockIdx.x * blockDim.x + threadIdx.x;
    if (t >= K * N) return;
    int k = t / N, n = t - k * N;
    Wt[(size_t)n * K + k] = f2bf(W[t]);
}

// ---------------- CSR build ----------------
__global__ void deg_count_k(const int* __restrict__ ei, int* __restrict__ deg) {
    int e = blockIdx.x * blockDim.x + threadIdx.x;
    if (e >= E_TOT) return;
    int d = (e < N_EDGESX) ? ei[N_EDGESX + e] : e - N_EDGESX;
    atomicAdd(&deg[d], 1);
}

// shuffle-based scan: 2 barriers per 1024-chunk
__global__ __launch_bounds__(1024) void scan_k(int* __restrict__ pos, int* __restrict__ rowptr) {
    __shared__ int wsum[16];
    __shared__ int carry_s;
    int tid = threadIdx.x, lane = tid & 63, w = tid >> 6;
    if (tid == 0) carry_s = 0;
    __syncthreads();
    for (int base = 0; base < N_NODES; base += 1024) {
        int i = base + tid;
        int v = (i < N_NODES) ? pos[i] : 0;
        int sc = v;
        #pragma unroll
        for (int off = 1; off < 64; off <<= 1) {
            int t = __shfl_up(sc, off);
            if (lane >= off) sc += t;
        }
        if (lane == 63) wsum[w] = sc;
        __syncthreads();
        if (w == 0 && lane < 16) {
            int s = wsum[lane];
            #pragma unroll
            for (int off = 1; off < 16; off <<= 1) {
                int t = __shfl_up(s, off);
                if (lane >= off) s += t;
            }
            wsum[lane] = s;
        }
        __syncthreads();
        int wbase = (w > 0) ? wsum[w - 1] : 0;
        int excl = carry_s + wbase + sc - v;
        if (i < N_NODES) { rowptr[i] = excl; pos[i] = excl; }
        __syncthreads();
        if (tid == 1023) carry_s += wsum[15];
        __syncthreads();
    }
    if (threadIdx.x == 0) rowptr[N_NODES] = carry_s;
}

__global__ void scatter_k(const int* __restrict__ ei, int* __restrict__ pos,
                          int* __restrict__ csr_src) {
    int e = blockIdx.x * blockDim.x + threadIdx.x;
    if (e >= E_TOT) return;
    int s, d;
    if (e < N_EDGESX) { s = ei[e]; d = ei[N_EDGESX + e]; }
    else              { s = e - N_EDGESX; d = s; }
    int idx = atomicAdd(&pos[d], 1);
    csr_src[idx] = s;
}

// ---------------- fused ONLINE softmax+aggregate, H=8, C=64, single edge pass ----------------
// lane = (e,h) for logits (e = lane>>3, h = lane&7); lane = channel for FMA.
__global__ __launch_bounds__(256) void node_agg8_k(
    const int* __restrict__ rowptr, const int* __restrict__ csr_src,
    const float* __restrict__ als, const float* __restrict__ ald,
    const unsigned short* __restrict__ hb, const float* __restrict__ bias,
    short* __restrict__ out) {
    int node = (blockIdx.x << 2) + (threadIdx.x >> 6);
    int lane = threadIdx.x & 63;
    if (node >= N_NODES) return;
    int beg = rowptr[node], end = rowptr[node + 1];
    int eh_e = lane >> 3, eh_h = lane & 7;
    float adv = ald[(size_t)node * 8 + eh_h];
    float m = -INFINITY, den = 0.f;
    float acc[8] = {};
    int i = beg + eh_e;
    int s_cur = csr_src[i < end ? i : (end - 1)];
    for (int c0 = beg; c0 < end; c0 += 8, i += 8) {
        bool valid = (i < end);
        int inx = i + 8;
        int s_next = csr_src[inx < end ? inx : (end - 1)];   // prefetch next chunk
        float v = lrelu(als[(size_t)s_cur * 8 + eh_h] + adv);
        float vm = valid ? v : -INFINITY;
        vm = fmaxf(vm, __shfl_xor(vm, 8));
        vm = fmaxf(vm, __shfl_xor(vm, 16));
        vm = fmaxf(vm, __shfl_xor(vm, 32));        // chunk max, per h, uniform over e
        float mnew = fmaxf(m, vm);
        float scale = expf(m - mnew);              // m=-inf -> 0
        float p = valid ? expf(v - mnew) : 0.f;
        den = den * scale + p;
        #pragma unroll
        for (int j = 0; j < 8; ++j) acc[j] *= __shfl(scale, j);   // lane j (e=0,h=j) holds scale[h=j]
        #pragma unroll
        for (int e = 0; e < 8; ++e) {
            if (c0 + e >= end) break;              // uniform across wave
            int se = __shfl(s_cur, e * 8);
            const unsigned short* hrow = hb + (size_t)se * HH512;
            #pragma unroll
            for (int j = 0; j < 8; ++j) {
                float pj = __shfl(p, e * 8 + j);
                acc[j] += pj * bf2f(hrow[j * 64 + lane]);
            }
        }
        m = mnew;
        s_cur = s_next;
    }
    den += __shfl_xor(den, 8);
    den += __shfl_xor(den, 16);
    den += __shfl_xor(den, 32);
    size_t ob = (size_t)node * HH512;
    #pragma unroll
    for (int j = 0; j < 8; ++j) {
        float dj = __shfl(den, j);
        float r = acc[j] / (dj + 1e-16f) + bias[j * 64 + lane];
        out[ob + j * 64 + lane] = f2bf(fmaxf(r, 0.f));
    }
}

// ---------------- final layer: H=1, C=47, ONLINE softmax + bias + log_softmax ----------------
__global__ __launch_bounds__(256) void node_agg_final_k(
    const int* __restrict__ rowptr, const int* __restrict__ csr_src,
    const float* __restrict__ als, const float* __restrict__ ald,
    const unsigned short* __restrict__ hb, const float* __restrict__ b3,
    float* __restrict__ out) {
    int node = (blockIdx.x << 2) + (threadIdx.x >> 6);
    int lane = threadIdx.x & 63;
    if (node >= N_NODES) return;
    int beg = rowptr[node], end = rowptr[node + 1];
    float ad = ald[node];
    float m = -INFINITY, den = 0.f, acc = 0.f;
    int i = beg + lane;
    int s_cur = csr_src[i < end ? i : (end - 1)];
    for (int c0 = beg; c0 < end; c0 += 64, i += 64) {
        bool valid = (i < end);
        int inx = i + 64;
        int s_next = csr_src[inx < end ? inx : (end - 1)];   // prefetch
        float v = lrelu(als[s_cur] + ad);
        float vm = valid ? v : -INFINITY;
        #pragma unroll
        for (int off = 32; off; off >>= 1) vm = fmaxf(vm, __shfl_xor(vm, off));  // wave-uniform
        float mnew = fmaxf(m, vm);
        float scale = expf(m - mnew);
        float p = valid ? expf(v - mnew) : 0.f;
        den = den * scale + p;
        acc *= scale;                               // scale wave-uniform
        #pragma unroll 4
        for (int e = 0; e < 64; ++e) {
            if (c0 + e >= end) break;               // uniform across wave
            int se = __shfl(s_cur, e);
            float pe = __shfl(p, e);
            if (lane < OUTC) acc += pe * bf2f(hb[(size_t)se * OUTC + lane]);
        }
        m = mnew;
        s_cur = s_next;
    }
    #pragma unroll
    for (int off = 32; off; off >>= 1) den += __shfl_xor(den, off);
    float r = (lane < OUTC) ? acc / (den + 1e-16f) + b3[lane] : -INFINITY;
    float mx = r;
    #pragma unroll
    for (int off = 32; off; off >>= 1) mx = fmaxf(mx, __shfl_xor(mx, off));
    float ex = (lane < OUTC) ? expf(r - mx) : 0.f;
    float sum = ex;
    #pragma unroll
    for (int off = 32; off; off >>= 1) sum += __shfl_xor(sum, off);
    if (lane < OUTC) out[(size_t)node * OUTC + lane] = r - mx - logf(sum);
}

static inline int cdiv(long long a, long long b) { return (int)((a + b - 1) / b); }

extern "C" void kernel_launch(void* const* d_in, const int* in_sizes, int n_in,
                              void* d_out, int out_size, void* d_ws, size_t ws_size,
                              hipStream_t stream) {
    const float* x   = (const float*)d_in[0];
    const int*   ei  = (const int*)d_in[1];
    const float* W1  = (const float*)d_in[2];
    const float* as1 = (const float*)d_in[3];
    const float* ad1 = (const float*)d_in[4];
    const float* b1  = (const float*)d_in[5];
    const float* W2  = (const float*)d_in[6];
    const float* as2 = (const float*)d_in[7];
    const float* ad2 = (const float*)d_in[8];
    const float* b2  = (const float*)d_in[9];
    const float* W3  = (const float*)d_in[10];
    const float* as3 = (const float*)d_in[11];
    const float* ad3 = (const float*)d_in[12];
    const float* b3  = (const float*)d_in[13];
    float* out = (float*)d_out;

    short* Abf = (short*)d_ws;                                     // [N,512] bf16
    unsigned short* Hb = (unsigned short*)(Abf + (size_t)N_NODES * HH512); // [N,512] bf16
    float* als = (float*)(Hb + (size_t)N_NODES * HH512);           // [N,8]
    float* ald = als + (size_t)N_NODES * HEADS;                    // [N,8]
    short* Wt  = (short*)(ald + (size_t)N_NODES * HEADS);          // [512,512] bf16
    int* rowptr  = (int*)(Wt + (size_t)HH512 * HH512);             // [N+1]
    int* pos     = rowptr + (N_NODES + 1);                         // [N]
    int* csr_src = pos + N_NODES;                                  // [E_TOT]

    dim3 blk(256);

    // ---- CSR build (reused by all 3 layers) ----
    hipMemsetAsync(pos, 0, (size_t)N_NODES * 4, stream);
    deg_count_k<<<cdiv(E_TOT, 256), blk, 0, stream>>>(ei, pos);
    scan_k<<<1, 1024, 0, stream>>>(pos, rowptr);
    scatter_k<<<cdiv(E_TOT, 256), blk, 0, stream>>>(ei, pos, csr_src);

    // ================= Layer 1 =================
    cast_bf16_k<<<cdiv((long long)N_NODES * 256 / 4, 256), blk, 0, stream>>>(x, Abf, (long long)N_NODES * 256);
    wt_cast_k<<<cdiv(256 * HH512, 256), blk, 0, stream>>>(W1, Wt, 256, HH512);
    gemm_bf16<<<dim3(cdiv(N_NODES, GBM), HH512 / GBN), blk, 0, stream>>>(
        Abf, Wt, Hb, N_NODES, HH512, 256, as1, ad1, als, ald, 64, HEADS);
    node_agg8_k<<<cdiv(N_NODES, 4), blk, 0, stream>>>(rowptr, csr_src, als, ald, Hb, b1, Abf);

    // ================= Layer 2 =================
    wt_cast_k<<<cdiv(HH512 * HH512, 256), blk, 0, stream>>>(W2, Wt, HH512, HH512);
    gemm_bf16<<<dim3(cdiv(N_NODES, GBM), HH512 / GBN), blk, 0, stream>>>(
        Abf, Wt, Hb, N_NODES, HH512, HH512, as2, ad2, als, ald, 64, HEADS);
    node_agg8_k<<<cdiv(N_NODES, 4), blk, 0, stream>>>(rowptr, csr_src, als, ald, Hb, b2, Abf);

    // ================= Layer 3 =================
    wt_cast_k<<<cdiv(HH512 * OUTC, 256), blk, 0, stream>>>(W3, Wt, HH512, OUTC);
    gemm_bf16<<<dim3(cdiv(N_NODES, GBM), 1), blk, 0, stream>>>(
        Abf, Wt, Hb, N_NODES, OUTC, HH512, as3, ad3, als, ald, 47, 1);
    node_agg_final_k<<<cdiv(N_NODES, 4), blk, 0, stream>>>(rowptr, csr_src, als, ald, Hb, b3, out);
}